// Round 4
// baseline (1748.170 us; speedup 1.0000x reference)
//
#include <hip/hip_runtime.h>
#include <math.h>

#define NN 10000
#define NE 160000
#define NG 64
#define NT 5
#define NL 4
#define ADL 2.833213344056216f

// ws layout (float offsets)
#define OFF_H      0
#define OFF_HC     750000
#define OFF_P      1500000     // P during agg; reused as `post` [N,75] after k_agg
#define OFF_Q      5250000
#define OFF_AGG    9000000
#define OFF_RLUT   24000000
#define OFF_INVDEG 24006000
#define OFF_AMP    24016000
#define OFF_ATT    24026000
#define OFF_STATS  24036000
#define OFF_GPOOL  24036160
#define OFF_INT    24118960

__global__ void k_zero_cnt(int* cnt){
    int i = blockIdx.x*256 + threadIdx.x;
    if (i < NN) cnt[i] = 0;
}

// h0 = node_emb[x].reshape(N,150) @ pre_lin_W + b
__global__ __launch_bounds__(256) void k_h0(const int* __restrict__ x,
        const float* __restrict__ node_emb, const float* __restrict__ plW,
        const float* __restrict__ plb, float* __restrict__ h){
    __shared__ float s_emb[21*75];
    __shared__ float s_W[150*75];
    __shared__ float s_b[75];
    int tid = threadIdx.x;
    for (int i = tid; i < 21*75; i += 256) s_emb[i] = node_emb[i];
    for (int i = tid; i < 150*75; i += 256) s_W[i] = plW[i];
    if (tid < 75) s_b[tid] = plb[tid];
    __syncthreads();
    for (int out = blockIdx.x*256 + tid; out < NN*75; out += gridDim.x*256){
        int n = out / 75, f = out - n*75;
        int x0 = x[2*n], x1 = x[2*n+1];
        float acc = s_b[f];
        const float* e0 = s_emb + x0*75;
        const float* e1 = s_emb + x1*75;
        #pragma unroll 5
        for (int k = 0; k < 75; k++)
            acc += e0[k]*s_W[k*75+f] + e1[k]*s_W[(75+k)*75+f];
        h[out] = acc;
    }
}

__global__ void k_hist(const int* __restrict__ ei, int* __restrict__ cnt){
    int e = blockIdx.x*256 + threadIdx.x;
    if (e < NE) atomicAdd(&cnt[ei[NE + e]], 1);
}

// single-block prefix sum: eoff[0]=0, eoff[n+1]=inclusive prefix
__global__ void k_scan(const int* __restrict__ cnt, int* __restrict__ eoff){
    __shared__ int buf[256];
    __shared__ int carry;
    int tid = threadIdx.x;
    if (tid == 0){ carry = 0; eoff[0] = 0; }
    __syncthreads();
    for (int base = 0; base < NN; base += 256){
        int v = (base + tid < NN) ? cnt[base + tid] : 0;
        buf[tid] = v; __syncthreads();
        for (int off = 1; off < 256; off <<= 1){
            int t2 = (tid >= off) ? buf[tid - off] : 0;
            __syncthreads();
            buf[tid] += t2;
            __syncthreads();
        }
        int inc = buf[tid] + carry;
        if (base + tid < NN) eoff[base + tid + 1] = inc;
        __syncthreads();
        if (tid == 255) carry = inc;
        __syncthreads();
    }
}

__global__ void k_nodestats(const int* __restrict__ cnt, const int* __restrict__ eoff,
        float* __restrict__ invdeg, float* __restrict__ amp, float* __restrict__ att,
        int* __restrict__ cursor){
    int n = blockIdx.x*256 + threadIdx.x;
    if (n >= NN) return;
    int c = cnt[n];
    cursor[n] = eoff[n];
    float cf = (float)c;
    float dg = cf < 1.f ? 1.f : cf;
    invdeg[n] = 1.f / dg;
    float ld = logf(dg + 1.f);
    amp[n] = ld / ADL;
    att[n] = ADL / ld;
}

__global__ void k_scatter(const int* __restrict__ ei, const int* __restrict__ ea,
        int* __restrict__ cursor, int* __restrict__ esrc, int* __restrict__ ecombo){
    int e = blockIdx.x*256 + threadIdx.x;
    if (e >= NE) return;
    int src = ei[e], dst = ei[NE + e];
    int pos = atomicAdd(&cursor[dst], 1);
    esrc[pos] = src;
    ecombo[pos] = ea[2*e]*4 + ea[2*e+1];
}

// R_lut[combo][j] = (e-vector for combo) @ Wc + pre_b  (16x375); block 16 zeroes BN stats
__global__ void k_rlut(const float* __restrict__ edge_emb, const float* __restrict__ encW,
        const float* __restrict__ encb, const float* __restrict__ preW,
        const float* __restrict__ preb, int l, float* __restrict__ Rlut,
        float* __restrict__ stats){
    int b = blockIdx.x, tid = threadIdx.x;
    if (b == 16){
        for (int i = tid; i < 150; i += 128) stats[i] = 0.f;
        return;
    }
    int a0 = b >> 2, a1 = b & 3;
    __shared__ float ev[75];
    if (tid < 75){
        int m = tid;
        float s = encb[l*75 + m];
        for (int k = 0; k < 25; k++) s += edge_emb[a0*25+k]*encW[((size_t)l*50+k)*75+m];
        for (int k = 0; k < 25; k++) s += edge_emb[a1*25+k]*encW[((size_t)l*50+25+k)*75+m];
        ev[m] = s;
    }
    __syncthreads();
    for (int j = tid; j < 375; j += 128){
        int t = j/75, f = j - 75*t;
        float r = preb[((size_t)l*NT + t)*75 + f];
        const float* w = preW + (((size_t)(l*NT + t))*225 + 150)*75 + f;
        for (int m = 0; m < 75; m++) r += ev[m]*w[m*75];
        Rlut[b*375 + j] = r;
    }
}

// P = h @ Wa (rows 0..74 of pre_W), Q = h @ Wb (rows 75..149); [10000,75]x[75,375]
__global__ __launch_bounds__(384) void k_pq(const float* __restrict__ h,
        const float* __restrict__ preW, int l, float* __restrict__ P, float* __restrict__ Q){
    __shared__ float h_t[32*76];
    int tid = threadIdx.x;
    int base = blockIdx.x*32;
    for (int idx = tid; idx < 32*75; idx += 384){
        int i = idx/75, m = idx - 75*i;
        int n = base + i;
        h_t[i*76 + m] = (n < NN) ? h[(size_t)n*75 + m] : 0.f;
    }
    __syncthreads();
    int j = tid;
    if (j >= 375) return;
    int t = j/75, f = j - 75*t;
    const float* wbase = preW + ((size_t)(l*NT + t))*225*75 + f;
    float accP[32], accQ[32];
    #pragma unroll
    for (int i = 0; i < 32; i++){ accP[i] = 0.f; accQ[i] = 0.f; }
    for (int m = 0; m < 72; m += 4){
        float wa0 = wbase[(m+0)*75], wa1 = wbase[(m+1)*75];
        float wa2 = wbase[(m+2)*75], wa3 = wbase[(m+3)*75];
        float wb0 = wbase[(75+m+0)*75], wb1 = wbase[(75+m+1)*75];
        float wb2 = wbase[(75+m+2)*75], wb3 = wbase[(75+m+3)*75];
        #pragma unroll
        for (int i = 0; i < 32; i++){
            const float4 hv = *(const float4*)&h_t[i*76 + m];
            accP[i] += hv.x*wa0 + hv.y*wa1 + hv.z*wa2 + hv.w*wa3;
            accQ[i] += hv.x*wb0 + hv.y*wb1 + hv.z*wb2 + hv.w*wb3;
        }
    }
    for (int m = 72; m < 75; m++){
        float wa = wbase[m*75], wb = wbase[(75+m)*75];
        #pragma unroll
        for (int i = 0; i < 32; i++){
            float v = h_t[i*76 + m];
            accP[i] += v*wa; accQ[i] += v*wb;
        }
    }
    for (int i = 0; i < 32; i++){
        int n = base + i;
        if (n < NN){ P[(size_t)n*375 + j] = accP[i]; Q[(size_t)n*375 + j] = accQ[i]; }
    }
}

// one block per node: msgs[e] = P[n] + Q[src] + R_lut[combo]; sum/sumsq/min/max -> agg[N,T,300]
__global__ __launch_bounds__(128) void k_agg(const float* __restrict__ P,
        const float* __restrict__ Q, const float* __restrict__ Rlut,
        const int* __restrict__ eoff, const int* __restrict__ esrc,
        const int* __restrict__ ecombo, const float* __restrict__ invdeg,
        float* __restrict__ agg){
    int n = blockIdx.x, tid = threadIdx.x;
    int lo = eoff[n], hi = eoff[n+1];
    float p[3], sum[3] = {0,0,0}, sq[3] = {0,0,0}, mn[3], mx[3];
    #pragma unroll
    for (int c = 0; c < 3; c++){
        int j = tid + c*128;
        p[c] = (j < 375) ? P[(size_t)n*375 + j] : 0.f;
        mn[c] = 3.4e38f; mx[c] = -3.4e38f;
    }
    for (int e = lo; e < hi; e++){
        int s = esrc[e], cm = ecombo[e];
        const float* q = Q + (size_t)s*375;
        const float* r = Rlut + cm*375;
        #pragma unroll
        for (int c = 0; c < 3; c++){
            int j = tid + c*128;
            if (j < 375){
                float m = p[c] + q[j] + r[j];
                sum[c] += m; sq[c] += m*m;
                mn[c] = fminf(mn[c], m); mx[c] = fmaxf(mx[c], m);
            }
        }
    }
    float id = invdeg[n];
    bool has = hi > lo;
    #pragma unroll
    for (int c = 0; c < 3; c++){
        int j = tid + c*128;
        if (j >= 375) continue;
        float mean = sum[c]*id;
        float msq  = sq[c]*id;
        float var = msq - mean*mean; var = var > 0.f ? var : 0.f;
        float sd = sqrtf(var + 1e-5f);
        float mnv = has ? mn[c] : 0.f;
        float mxv = has ? mx[c] : 0.f;
        int t = j/75, f = j - 75*t;
        float* a = agg + ((size_t)n*NT + t)*300;
        a[f] = mean; a[75+f] = mnv; a[150+f] = mxv; a[225+f] = sd;
    }
}

// post einsum: one tower's weights (975x16 padded, 62.4 KB) in LDS, 64 nodes/block.
// thread = (node sub 0..63, fgroup 0..3); amp/att/bias folded here.
// grid (157, 5), block 256.
__global__ __launch_bounds__(256) void k_post(const float* __restrict__ h,
        const float* __restrict__ agg, const float* __restrict__ postW,
        const float* __restrict__ postb, const float* __restrict__ amp,
        const float* __restrict__ att, int l, float* __restrict__ post){
    __shared__ float sW[975*16];
    int t = blockIdx.y;
    const float* wsrc = postW + ((size_t)(l*NT + t))*975*15;
    for (int i = threadIdx.x; i < 975*16; i += 256){
        int k = i >> 4, f = i & 15;
        sW[i] = (f < 15) ? wsrc[k*15 + f] : 0.f;
    }
    __syncthreads();
    int sub = threadIdx.x >> 2;
    int fg  = (threadIdx.x & 3)*4;
    int n = blockIdx.x*64 + sub;
    if (n >= NN) return;
    const float* ag = agg + (size_t)n*1500 + t*300;
    const float* hn = h + (size_t)n*75;
    float h0=0,h1=0,h2=0,h3=0;
    float a10=0,a11=0,a12=0,a13=0;
    float a20=0,a21=0,a22=0,a23=0;
    float a30=0,a31=0,a32=0,a33=0;
    for (int k = 0; k < 75; k++){
        float v = hn[k];
        const float4 w = *(const float4*)&sW[k*16 + fg];
        h0 += v*w.x; h1 += v*w.y; h2 += v*w.z; h3 += v*w.w;
    }
    #pragma unroll 4
    for (int k = 0; k < 300; k++){
        float v = ag[k];
        const float4 w1 = *(const float4*)&sW[(75+k)*16 + fg];
        const float4 w2 = *(const float4*)&sW[(375+k)*16 + fg];
        const float4 w3 = *(const float4*)&sW[(675+k)*16 + fg];
        a10 += v*w1.x; a11 += v*w1.y; a12 += v*w1.z; a13 += v*w1.w;
        a20 += v*w2.x; a21 += v*w2.y; a22 += v*w2.z; a23 += v*w2.w;
        a30 += v*w3.x; a31 += v*w3.y; a32 += v*w3.z; a33 += v*w3.w;
    }
    float am = amp[n], at = att[n];
    const float* pb = postb + (l*NT + t)*15;
    float* dst = post + (size_t)n*75 + t*15;
    float r0 = h0 + a10 + am*a20 + at*a30;
    float r1 = h1 + a11 + am*a21 + at*a31;
    float r2 = h2 + a12 + am*a22 + at*a32;
    float r3 = h3 + a13 + am*a23 + at*a33;
    dst[fg+0] = r0 + pb[fg+0];
    dst[fg+1] = r1 + pb[fg+1];
    dst[fg+2] = r2 + pb[fg+2];
    if (fg+3 < 15) dst[fg+3] = r3 + pb[fg+3];
}

// hc = post @ lin_W[l] + lin_b[l]; fused per-block BN-stat reduction (replaces k_bnstats)
__global__ __launch_bounds__(256) void k_lin(const float* __restrict__ post,
        const float* __restrict__ linW, const float* __restrict__ linb,
        int l, float* __restrict__ hc, float* __restrict__ stats){
    __shared__ float p_l[32*75];
    __shared__ float w_l[75*75];
    __shared__ float hc_l[32*75];
    int tid = threadIdx.x;
    int base = blockIdx.x*32;
    for (int i = tid; i < 75*75; i += 256) w_l[i] = linW[(size_t)l*5625 + i];
    for (int i = tid; i < 32*75; i += 256){
        int n = base + i/75;
        p_l[i] = (n < NN) ? post[(size_t)base*75 + i] : 0.f;
    }
    __syncthreads();
    for (int task = tid; task < 2400; task += 256){
        int i = task/75, o = task - 75*i;
        float s = linb[l*75 + o];
        const float* pl = p_l + i*75;
        #pragma unroll 5
        for (int j = 0; j < 75; j++) s += pl[j]*w_l[j*75 + o];
        hc_l[task] = s;
        if (base + i < NN) hc[(size_t)(base+i)*75 + o] = s;
    }
    __syncthreads();
    if (tid < 75){
        int nv = NN - base; if (nv > 32) nv = 32;
        float s1 = 0.f, s2 = 0.f;
        for (int i = 0; i < nv; i++){
            float v = hc_l[i*75 + tid];
            s1 += v; s2 += v*v;
        }
        atomicAdd(&stats[tid], s1);
        atomicAdd(&stats[75+tid], s2);
    }
}

__global__ void k_bnapply(const float* __restrict__ hc, const float* __restrict__ stats,
        const float* __restrict__ bng, const float* __restrict__ bnb, int l,
        float* __restrict__ h){
    int idx = blockIdx.x*256 + threadIdx.x;
    if (idx >= NN*75) return;
    int col = idx % 75;
    float mu = stats[col]*(1.0f/NN);
    float var = stats[75+col]*(1.0f/NN) - mu*mu;
    float inv = rsqrtf(var + 1e-5f);
    float v = (hc[idx] - mu)*inv*bng[l*75+col] + bnb[l*75+col];
    h[idx] = v > 0.f ? v : 0.f;
}

__global__ __launch_bounds__(256) void k_pool(const float* __restrict__ h,
        const int* __restrict__ batch, float* __restrict__ gpool){
    int g = blockIdx.x, tid = threadIdx.x;
    int lo = 0, hi = NN;
    while (lo < hi){ int mid = (lo+hi)>>1; if (batch[mid] < g) lo = mid+1; else hi = mid; }
    int start = lo;
    lo = start; hi = NN;
    while (lo < hi){ int mid = (lo+hi)>>1; if (batch[mid] < g+1) lo = mid+1; else hi = mid; }
    int end = lo;
    __shared__ float red[225];
    if (tid < 225){
        int col = tid % 75, rep = tid / 75;
        float acc = 0.f;
        for (int i = start + rep; i < end; i += 3) acc += h[(size_t)i*75 + col];
        red[tid] = acc;
    }
    __syncthreads();
    if (tid < 75) gpool[g*75 + tid] = red[tid] + red[75+tid] + red[150+tid];
}

// 8 blocks x 8 graphs; weights in LDS, phase-parallel
__global__ __launch_bounds__(256) void k_mlp(const float* __restrict__ gpool,
        const float* __restrict__ W1, const float* __restrict__ b1,
        const float* __restrict__ W2, const float* __restrict__ b2,
        const float* __restrict__ W3, const float* __restrict__ b3,
        float* __restrict__ out){
    __shared__ float w1[75*50];
    __shared__ float w2[50*25];
    __shared__ float gp[8*75];
    __shared__ float t1[8*50];
    __shared__ float t2[8*25];
    int tid = threadIdx.x;
    int gbase = blockIdx.x*8;
    for (int i = tid; i < 75*50; i += 256) w1[i] = W1[i];
    for (int i = tid; i < 50*25; i += 256) w2[i] = W2[i];
    for (int i = tid; i < 8*75; i += 256) gp[i] = gpool[gbase*75 + i];
    __syncthreads();
    for (int task = tid; task < 8*50; task += 256){
        int g = task/50, j = task - 50*g;
        float s = b1[j];
        const float* gv = gp + g*75;
        #pragma unroll 5
        for (int k = 0; k < 75; k++) s += gv[k]*w1[k*50+j];
        t1[task] = s > 0.f ? s : 0.f;
    }
    __syncthreads();
    for (int task = tid; task < 8*25; task += 256){
        int g = task/25, j = task - 25*g;
        float s = b2[j];
        const float* tv = t1 + g*50;
        #pragma unroll 5
        for (int k = 0; k < 50; k++) s += tv[k]*w2[k*25+j];
        t2[task] = s > 0.f ? s : 0.f;
    }
    __syncthreads();
    if (tid < 8){
        float s = b3[0];
        const float* tv = t2 + tid*25;
        #pragma unroll
        for (int k = 0; k < 25; k++) s += tv[k]*W3[k];
        out[gbase + tid] = s;
    }
}

extern "C" void kernel_launch(void* const* d_in, const int* in_sizes, int n_in,
                              void* d_out, int out_size, void* d_ws, size_t ws_size,
                              hipStream_t stream){
    const int* x          = (const int*)d_in[0];
    const int* edge_index = (const int*)d_in[1];
    const int* edge_attr  = (const int*)d_in[2];
    const int* batch      = (const int*)d_in[3];
    const float* node_emb = (const float*)d_in[4];
    const float* edge_emb = (const float*)d_in[5];
    const float* pre_lin_W= (const float*)d_in[6];
    const float* pre_lin_b= (const float*)d_in[7];
    const float* encW     = (const float*)d_in[8];
    const float* encb     = (const float*)d_in[9];
    const float* preW     = (const float*)d_in[10];
    const float* preb     = (const float*)d_in[11];
    const float* postW    = (const float*)d_in[12];
    const float* postb    = (const float*)d_in[13];
    const float* linW     = (const float*)d_in[14];
    const float* linb     = (const float*)d_in[15];
    const float* bng      = (const float*)d_in[16];
    const float* bnb      = (const float*)d_in[17];
    const float* mlpW1    = (const float*)d_in[18];
    const float* mlpb1    = (const float*)d_in[19];
    const float* mlpW2    = (const float*)d_in[20];
    const float* mlpb2    = (const float*)d_in[21];
    const float* mlpW3    = (const float*)d_in[22];
    const float* mlpb3    = (const float*)d_in[23];

    float* ws = (float*)d_ws;
    float* h      = ws + OFF_H;
    float* hc     = ws + OFF_HC;
    float* P      = ws + OFF_P;
    float* Q      = ws + OFF_Q;
    float* agg    = ws + OFF_AGG;
    float* Rlut   = ws + OFF_RLUT;
    float* invdeg = ws + OFF_INVDEG;
    float* amp    = ws + OFF_AMP;
    float* att    = ws + OFF_ATT;
    float* stats  = ws + OFF_STATS;
    float* gpool  = ws + OFF_GPOOL;
    float* post   = ws + OFF_P;     // reuses P region (P dead after k_agg)
    int* iw     = (int*)(ws + OFF_INT);
    int* cnt    = iw;
    int* eoff   = cnt + NN;        // NN+1
    int* cursor = eoff + NN + 2;
    int* esrc   = cursor + NN;
    int* ecombo = esrc + NE;

    k_zero_cnt<<<40, 256, 0, stream>>>(cnt);
    k_h0<<<640, 256, 0, stream>>>(x, node_emb, pre_lin_W, pre_lin_b, h);
    k_hist<<<625, 256, 0, stream>>>(edge_index, cnt);
    k_scan<<<1, 256, 0, stream>>>(cnt, eoff);
    k_nodestats<<<40, 256, 0, stream>>>(cnt, eoff, invdeg, amp, att, cursor);
    k_scatter<<<625, 256, 0, stream>>>(edge_index, edge_attr, cursor, esrc, ecombo);

    for (int l = 0; l < NL; l++){
        k_rlut<<<17, 128, 0, stream>>>(edge_emb, encW, encb, preW, preb, l, Rlut, stats);
        k_pq<<<313, 384, 0, stream>>>(h, preW, l, P, Q);
        k_agg<<<NN, 128, 0, stream>>>(P, Q, Rlut, eoff, esrc, ecombo, invdeg, agg);
        k_post<<<dim3(157, 5), 256, 0, stream>>>(h, agg, postW, postb, amp, att, l, post);
        k_lin<<<313, 256, 0, stream>>>(post, linW, linb, l, hc, stats);
        k_bnapply<<<2930, 256, 0, stream>>>(hc, stats, bng, bnb, l, h);
    }

    k_pool<<<NG, 256, 0, stream>>>(h, batch, gpool);
    k_mlp<<<8, 256, 0, stream>>>(gpool, mlpW1, mlpb1, mlpW2, mlpb2, mlpW3, mlpb3, (float*)d_out);
}

// Round 5
// 1718.204 us; speedup vs baseline: 1.0174x; 1.0174x over previous
//
#include <hip/hip_runtime.h>
#include <math.h>

#define NN 10000
#define NE 160000
#define NG 64
#define NT 5
#define NL 4
#define ADL 2.833213344056216f

// ws layout (float offsets)
#define OFF_H      0
#define OFF_HC     750000
#define OFF_P      1500000     // P during agg; reused as `post` [N,75] after k_agg
#define OFF_Q      5250000
#define OFF_AGG    9000000
#define OFF_RLUT   24000000
#define OFF_INVDEG 24006000
#define OFF_AMP    24016000
#define OFF_ATT    24026000
#define OFF_STATS  24036000
#define OFF_GPOOL  24036160
#define OFF_INT    24118960

__global__ void k_zero_cnt(int* cnt){
    int i = blockIdx.x*256 + threadIdx.x;
    if (i < NN) cnt[i] = 0;
}

// h0 = node_emb[x].reshape(N,150) @ pre_lin_W + b
__global__ __launch_bounds__(256) void k_h0(const int* __restrict__ x,
        const float* __restrict__ node_emb, const float* __restrict__ plW,
        const float* __restrict__ plb, float* __restrict__ h){
    __shared__ float s_emb[21*75];
    __shared__ float s_W[150*75];
    __shared__ float s_b[75];
    int tid = threadIdx.x;
    for (int i = tid; i < 21*75; i += 256) s_emb[i] = node_emb[i];
    for (int i = tid; i < 150*75; i += 256) s_W[i] = plW[i];
    if (tid < 75) s_b[tid] = plb[tid];
    __syncthreads();
    for (int out = blockIdx.x*256 + tid; out < NN*75; out += gridDim.x*256){
        int n = out / 75, f = out - n*75;
        int x0 = x[2*n], x1 = x[2*n+1];
        float acc = s_b[f];
        const float* e0 = s_emb + x0*75;
        const float* e1 = s_emb + x1*75;
        #pragma unroll 5
        for (int k = 0; k < 75; k++)
            acc += e0[k]*s_W[k*75+f] + e1[k]*s_W[(75+k)*75+f];
        h[out] = acc;
    }
}

__global__ void k_hist(const int* __restrict__ ei, int* __restrict__ cnt){
    int e = blockIdx.x*256 + threadIdx.x;
    if (e < NE) atomicAdd(&cnt[ei[NE + e]], 1);
}

// single-block prefix sum: eoff[0]=0, eoff[n+1]=inclusive prefix
__global__ void k_scan(const int* __restrict__ cnt, int* __restrict__ eoff){
    __shared__ int buf[256];
    __shared__ int carry;
    int tid = threadIdx.x;
    if (tid == 0){ carry = 0; eoff[0] = 0; }
    __syncthreads();
    for (int base = 0; base < NN; base += 256){
        int v = (base + tid < NN) ? cnt[base + tid] : 0;
        buf[tid] = v; __syncthreads();
        for (int off = 1; off < 256; off <<= 1){
            int t2 = (tid >= off) ? buf[tid - off] : 0;
            __syncthreads();
            buf[tid] += t2;
            __syncthreads();
        }
        int inc = buf[tid] + carry;
        if (base + tid < NN) eoff[base + tid + 1] = inc;
        __syncthreads();
        if (tid == 255) carry = inc;
        __syncthreads();
    }
}

__global__ void k_nodestats(const int* __restrict__ cnt, const int* __restrict__ eoff,
        float* __restrict__ invdeg, float* __restrict__ amp, float* __restrict__ att,
        int* __restrict__ cursor){
    int n = blockIdx.x*256 + threadIdx.x;
    if (n >= NN) return;
    int c = cnt[n];
    cursor[n] = eoff[n];
    float cf = (float)c;
    float dg = cf < 1.f ? 1.f : cf;
    invdeg[n] = 1.f / dg;
    float ld = logf(dg + 1.f);
    amp[n] = ld / ADL;
    att[n] = ADL / ld;
}

__global__ void k_scatter(const int* __restrict__ ei, const int* __restrict__ ea,
        int* __restrict__ cursor, int* __restrict__ esrc, int* __restrict__ ecombo){
    int e = blockIdx.x*256 + threadIdx.x;
    if (e >= NE) return;
    int src = ei[e], dst = ei[NE + e];
    int pos = atomicAdd(&cursor[dst], 1);
    esrc[pos] = src;
    ecombo[pos] = ea[2*e]*4 + ea[2*e+1];
}

// R_lut[combo][j] = (e-vector for combo) @ Wc + pre_b  (16x375); block 16 zeroes BN stats
__global__ void k_rlut(const float* __restrict__ edge_emb, const float* __restrict__ encW,
        const float* __restrict__ encb, const float* __restrict__ preW,
        const float* __restrict__ preb, int l, float* __restrict__ Rlut,
        float* __restrict__ stats){
    int b = blockIdx.x, tid = threadIdx.x;
    if (b == 16){
        for (int i = tid; i < 150; i += 128) stats[i] = 0.f;
        return;
    }
    int a0 = b >> 2, a1 = b & 3;
    __shared__ float ev[75];
    if (tid < 75){
        int m = tid;
        float s = encb[l*75 + m];
        for (int k = 0; k < 25; k++) s += edge_emb[a0*25+k]*encW[((size_t)l*50+k)*75+m];
        for (int k = 0; k < 25; k++) s += edge_emb[a1*25+k]*encW[((size_t)l*50+25+k)*75+m];
        ev[m] = s;
    }
    __syncthreads();
    for (int j = tid; j < 375; j += 128){
        int t = j/75, f = j - 75*t;
        float r = preb[((size_t)l*NT + t)*75 + f];
        const float* w = preW + (((size_t)(l*NT + t))*225 + 150)*75 + f;
        for (int m = 0; m < 75; m++) r += ev[m]*w[m*75];
        Rlut[b*375 + j] = r;
    }
}

// P = h @ Wa (rows 0..74 of pre_W), Q = h @ Wb (rows 75..149); [10000,75]x[75,375]
__global__ __launch_bounds__(384) void k_pq(const float* __restrict__ h,
        const float* __restrict__ preW, int l, float* __restrict__ P, float* __restrict__ Q){
    __shared__ float h_t[32*76];
    int tid = threadIdx.x;
    int base = blockIdx.x*32;
    for (int idx = tid; idx < 32*75; idx += 384){
        int i = idx/75, m = idx - 75*i;
        int n = base + i;
        h_t[i*76 + m] = (n < NN) ? h[(size_t)n*75 + m] : 0.f;
    }
    __syncthreads();
    int j = tid;
    if (j >= 375) return;
    int t = j/75, f = j - 75*t;
    const float* wbase = preW + ((size_t)(l*NT + t))*225*75 + f;
    float accP[32], accQ[32];
    #pragma unroll
    for (int i = 0; i < 32; i++){ accP[i] = 0.f; accQ[i] = 0.f; }
    for (int m = 0; m < 72; m += 4){
        float wa0 = wbase[(m+0)*75], wa1 = wbase[(m+1)*75];
        float wa2 = wbase[(m+2)*75], wa3 = wbase[(m+3)*75];
        float wb0 = wbase[(75+m+0)*75], wb1 = wbase[(75+m+1)*75];
        float wb2 = wbase[(75+m+2)*75], wb3 = wbase[(75+m+3)*75];
        #pragma unroll
        for (int i = 0; i < 32; i++){
            const float4 hv = *(const float4*)&h_t[i*76 + m];
            accP[i] += hv.x*wa0 + hv.y*wa1 + hv.z*wa2 + hv.w*wa3;
            accQ[i] += hv.x*wb0 + hv.y*wb1 + hv.z*wb2 + hv.w*wb3;
        }
    }
    for (int m = 72; m < 75; m++){
        float wa = wbase[m*75], wb = wbase[(75+m)*75];
        #pragma unroll
        for (int i = 0; i < 32; i++){
            float v = h_t[i*76 + m];
            accP[i] += v*wa; accQ[i] += v*wb;
        }
    }
    for (int i = 0; i < 32; i++){
        int n = base + i;
        if (n < NN){ P[(size_t)n*375 + j] = accP[i]; Q[(size_t)n*375 + j] = accQ[i]; }
    }
}

// one block per node: msgs[e] = P[n] + Q[src] + R_lut[combo]; sum/sumsq/min/max -> agg[N,T,300]
__global__ __launch_bounds__(128) void k_agg(const float* __restrict__ P,
        const float* __restrict__ Q, const float* __restrict__ Rlut,
        const int* __restrict__ eoff, const int* __restrict__ esrc,
        const int* __restrict__ ecombo, const float* __restrict__ invdeg,
        float* __restrict__ agg){
    int n = blockIdx.x, tid = threadIdx.x;
    int lo = eoff[n], hi = eoff[n+1];
    float p[3], sum[3] = {0,0,0}, sq[3] = {0,0,0}, mn[3], mx[3];
    #pragma unroll
    for (int c = 0; c < 3; c++){
        int j = tid + c*128;
        p[c] = (j < 375) ? P[(size_t)n*375 + j] : 0.f;
        mn[c] = 3.4e38f; mx[c] = -3.4e38f;
    }
    for (int e = lo; e < hi; e++){
        int s = esrc[e], cm = ecombo[e];
        const float* q = Q + (size_t)s*375;
        const float* r = Rlut + cm*375;
        #pragma unroll
        for (int c = 0; c < 3; c++){
            int j = tid + c*128;
            if (j < 375){
                float m = p[c] + q[j] + r[j];
                sum[c] += m; sq[c] += m*m;
                mn[c] = fminf(mn[c], m); mx[c] = fmaxf(mx[c], m);
            }
        }
    }
    float id = invdeg[n];
    bool has = hi > lo;
    #pragma unroll
    for (int c = 0; c < 3; c++){
        int j = tid + c*128;
        if (j >= 375) continue;
        float mean = sum[c]*id;
        float msq  = sq[c]*id;
        float var = msq - mean*mean; var = var > 0.f ? var : 0.f;
        float sd = sqrtf(var + 1e-5f);
        float mnv = has ? mn[c] : 0.f;
        float mxv = has ? mx[c] : 0.f;
        int t = j/75, f = j - 75*t;
        float* a = agg + ((size_t)n*NT + t)*300;
        a[f] = mean; a[75+f] = mnv; a[150+f] = mxv; a[225+f] = sd;
    }
}

// post einsum, LDS-tiled: block = 256 nodes x 1 tower, thread = (sub, fgroup) x 4 nodes.
// h-part folds into the unscaled accumulator (coefficient 1). grid (40, 5).
#define TK 25
#define PADA 27
__global__ __launch_bounds__(256, 4) void k_post(const float* __restrict__ h,
        const float* __restrict__ agg, const float* __restrict__ postW,
        const float* __restrict__ postb, const float* __restrict__ amp,
        const float* __restrict__ att, int l, float* __restrict__ post){
    __shared__ float s_a[256*PADA];      // 27.6 KB activation tile
    __shared__ float s_w[3][TK*16];      // 4.8 KB weight tiles (f padded to 16)
    int t = blockIdx.y;
    int nbase = blockIdx.x*256;
    int tid = threadIdx.x;
    int fg  = (tid & 3)*4;
    int sub = tid >> 2;
    const float* Wt = postW + ((size_t)(l*NT + t))*975*15;
    float a1[4][4], a2[4][4], a3[4][4];
    #pragma unroll
    for (int j = 0; j < 4; j++)
        #pragma unroll
        for (int f = 0; f < 4; f++){ a1[j][f]=0.f; a2[j][f]=0.f; a3[j][f]=0.f; }

    // ---- h-part: k = 0..74, weight rows 0..74, accumulates into a1 only ----
    for (int kt = 0; kt < 75; kt += TK){
        for (int idx = tid; idx < 256*TK; idx += 256){
            int row = idx / TK, c = idx - row*TK;
            int n = nbase + row;
            s_a[row*PADA + c] = (n < NN) ? h[(size_t)n*75 + kt + c] : 0.f;
        }
        for (int idx = tid; idx < TK*16; idx += 256){
            int c = idx >> 4, f = idx & 15;
            s_w[0][idx] = (f < 15) ? Wt[(kt + c)*15 + f] : 0.f;
        }
        __syncthreads();
        for (int k = 0; k < TK; k++){
            const float4 w1 = *(const float4*)&s_w[0][k*16 + fg];
            #pragma unroll
            for (int j = 0; j < 4; j++){
                float v = s_a[(sub + 64*j)*PADA + k];
                a1[j][0] += v*w1.x; a1[j][1] += v*w1.y;
                a1[j][2] += v*w1.z; a1[j][3] += v*w1.w;
            }
        }
        __syncthreads();
    }

    // ---- agg part: k = 0..299; weight rows 75+k (plain), 375+k (amp), 675+k (att) ----
    for (int kt = 0; kt < 300; kt += TK){
        for (int idx = tid; idx < 256*TK; idx += 256){
            int row = idx / TK, c = idx - row*TK;
            int n = nbase + row;
            s_a[row*PADA + c] = (n < NN) ? agg[(size_t)n*1500 + t*300 + kt + c] : 0.f;
        }
        for (int idx = tid; idx < TK*16; idx += 256){
            int c = idx >> 4, f = idx & 15;
            float v1 = 0.f, v2 = 0.f, v3 = 0.f;
            if (f < 15){
                v1 = Wt[( 75 + kt + c)*15 + f];
                v2 = Wt[(375 + kt + c)*15 + f];
                v3 = Wt[(675 + kt + c)*15 + f];
            }
            s_w[0][idx] = v1; s_w[1][idx] = v2; s_w[2][idx] = v3;
        }
        __syncthreads();
        for (int k = 0; k < TK; k++){
            const float4 w1 = *(const float4*)&s_w[0][k*16 + fg];
            const float4 w2 = *(const float4*)&s_w[1][k*16 + fg];
            const float4 w3 = *(const float4*)&s_w[2][k*16 + fg];
            #pragma unroll
            for (int j = 0; j < 4; j++){
                float v = s_a[(sub + 64*j)*PADA + k];
                a1[j][0] += v*w1.x; a1[j][1] += v*w1.y;
                a1[j][2] += v*w1.z; a1[j][3] += v*w1.w;
                a2[j][0] += v*w2.x; a2[j][1] += v*w2.y;
                a2[j][2] += v*w2.z; a2[j][3] += v*w2.w;
                a3[j][0] += v*w3.x; a3[j][1] += v*w3.y;
                a3[j][2] += v*w3.z; a3[j][3] += v*w3.w;
            }
        }
        __syncthreads();
    }

    const float* pb = postb + (l*NT + t)*15;
    #pragma unroll
    for (int j = 0; j < 4; j++){
        int n = nbase + sub + 64*j;
        if (n >= NN) continue;
        float am = amp[n], at = att[n];
        float* dst = post + (size_t)n*75 + t*15;
        #pragma unroll
        for (int f = 0; f < 4; f++){
            if (fg + f < 15)
                dst[fg + f] = a1[j][f] + am*a2[j][f] + at*a3[j][f] + pb[fg + f];
        }
    }
}

// hc = post @ lin_W[l] + lin_b[l]; fused per-block BN-stat reduction
__global__ __launch_bounds__(256) void k_lin(const float* __restrict__ post,
        const float* __restrict__ linW, const float* __restrict__ linb,
        int l, float* __restrict__ hc, float* __restrict__ stats){
    __shared__ float p_l[32*75];
    __shared__ float w_l[75*75];
    __shared__ float hc_l[32*75];
    int tid = threadIdx.x;
    int base = blockIdx.x*32;
    for (int i = tid; i < 75*75; i += 256) w_l[i] = linW[(size_t)l*5625 + i];
    for (int i = tid; i < 32*75; i += 256){
        int n = base + i/75;
        p_l[i] = (n < NN) ? post[(size_t)base*75 + i] : 0.f;
    }
    __syncthreads();
    for (int task = tid; task < 2400; task += 256){
        int i = task/75, o = task - 75*i;
        float s = linb[l*75 + o];
        const float* pl = p_l + i*75;
        #pragma unroll 5
        for (int j = 0; j < 75; j++) s += pl[j]*w_l[j*75 + o];
        hc_l[task] = s;
        if (base + i < NN) hc[(size_t)(base+i)*75 + o] = s;
    }
    __syncthreads();
    if (tid < 75){
        int nv = NN - base; if (nv > 32) nv = 32;
        float s1 = 0.f, s2 = 0.f;
        for (int i = 0; i < nv; i++){
            float v = hc_l[i*75 + tid];
            s1 += v; s2 += v*v;
        }
        atomicAdd(&stats[tid], s1);
        atomicAdd(&stats[75+tid], s2);
    }
}

__global__ void k_bnapply(const float* __restrict__ hc, const float* __restrict__ stats,
        const float* __restrict__ bng, const float* __restrict__ bnb, int l,
        float* __restrict__ h){
    int idx = blockIdx.x*256 + threadIdx.x;
    if (idx >= NN*75) return;
    int col = idx % 75;
    float mu = stats[col]*(1.0f/NN);
    float var = stats[75+col]*(1.0f/NN) - mu*mu;
    float inv = rsqrtf(var + 1e-5f);
    float v = (hc[idx] - mu)*inv*bng[l*75+col] + bnb[l*75+col];
    h[idx] = v > 0.f ? v : 0.f;
}

__global__ __launch_bounds__(256) void k_pool(const float* __restrict__ h,
        const int* __restrict__ batch, float* __restrict__ gpool){
    int g = blockIdx.x, tid = threadIdx.x;
    int lo = 0, hi = NN;
    while (lo < hi){ int mid = (lo+hi)>>1; if (batch[mid] < g) lo = mid+1; else hi = mid; }
    int start = lo;
    lo = start; hi = NN;
    while (lo < hi){ int mid = (lo+hi)>>1; if (batch[mid] < g+1) lo = mid+1; else hi = mid; }
    int end = lo;
    __shared__ float red[225];
    if (tid < 225){
        int col = tid % 75, rep = tid / 75;
        float acc = 0.f;
        for (int i = start + rep; i < end; i += 3) acc += h[(size_t)i*75 + col];
        red[tid] = acc;
    }
    __syncthreads();
    if (tid < 75) gpool[g*75 + tid] = red[tid] + red[75+tid] + red[150+tid];
}

// 8 blocks x 8 graphs; weights in LDS, phase-parallel
__global__ __launch_bounds__(256) void k_mlp(const float* __restrict__ gpool,
        const float* __restrict__ W1, const float* __restrict__ b1,
        const float* __restrict__ W2, const float* __restrict__ b2,
        const float* __restrict__ W3, const float* __restrict__ b3,
        float* __restrict__ out){
    __shared__ float w1[75*50];
    __shared__ float w2[50*25];
    __shared__ float gp[8*75];
    __shared__ float t1[8*50];
    __shared__ float t2[8*25];
    int tid = threadIdx.x;
    int gbase = blockIdx.x*8;
    for (int i = tid; i < 75*50; i += 256) w1[i] = W1[i];
    for (int i = tid; i < 50*25; i += 256) w2[i] = W2[i];
    for (int i = tid; i < 8*75; i += 256) gp[i] = gpool[gbase*75 + i];
    __syncthreads();
    for (int task = tid; task < 8*50; task += 256){
        int g = task/50, j = task - 50*g;
        float s = b1[j];
        const float* gv = gp + g*75;
        #pragma unroll 5
        for (int k = 0; k < 75; k++) s += gv[k]*w1[k*50+j];
        t1[task] = s > 0.f ? s : 0.f;
    }
    __syncthreads();
    for (int task = tid; task < 8*25; task += 256){
        int g = task/25, j = task - 25*g;
        float s = b2[j];
        const float* tv = t1 + g*50;
        #pragma unroll 5
        for (int k = 0; k < 50; k++) s += tv[k]*w2[k*25+j];
        t2[task] = s > 0.f ? s : 0.f;
    }
    __syncthreads();
    if (tid < 8){
        float s = b3[0];
        const float* tv = t2 + tid*25;
        #pragma unroll
        for (int k = 0; k < 25; k++) s += tv[k]*W3[k];
        out[gbase + tid] = s;
    }
}

extern "C" void kernel_launch(void* const* d_in, const int* in_sizes, int n_in,
                              void* d_out, int out_size, void* d_ws, size_t ws_size,
                              hipStream_t stream){
    const int* x          = (const int*)d_in[0];
    const int* edge_index = (const int*)d_in[1];
    const int* edge_attr  = (const int*)d_in[2];
    const int* batch      = (const int*)d_in[3];
    const float* node_emb = (const float*)d_in[4];
    const float* edge_emb = (const float*)d_in[5];
    const float* pre_lin_W= (const float*)d_in[6];
    const float* pre_lin_b= (const float*)d_in[7];
    const float* encW     = (const float*)d_in[8];
    const float* encb     = (const float*)d_in[9];
    const float* preW     = (const float*)d_in[10];
    const float* preb     = (const float*)d_in[11];
    const float* postW    = (const float*)d_in[12];
    const float* postb    = (const float*)d_in[13];
    const float* linW     = (const float*)d_in[14];
    const float* linb     = (const float*)d_in[15];
    const float* bng      = (const float*)d_in[16];
    const float* bnb      = (const float*)d_in[17];
    const float* mlpW1    = (const float*)d_in[18];
    const float* mlpb1    = (const float*)d_in[19];
    const float* mlpW2    = (const float*)d_in[20];
    const float* mlpb2    = (const float*)d_in[21];
    const float* mlpW3    = (const float*)d_in[22];
    const float* mlpb3    = (const float*)d_in[23];

    float* ws = (float*)d_ws;
    float* h      = ws + OFF_H;
    float* hc     = ws + OFF_HC;
    float* P      = ws + OFF_P;
    float* Q      = ws + OFF_Q;
    float* agg    = ws + OFF_AGG;
    float* Rlut   = ws + OFF_RLUT;
    float* invdeg = ws + OFF_INVDEG;
    float* amp    = ws + OFF_AMP;
    float* att    = ws + OFF_ATT;
    float* stats  = ws + OFF_STATS;
    float* gpool  = ws + OFF_GPOOL;
    float* post   = ws + OFF_P;     // reuses P region (P dead after k_agg)
    int* iw     = (int*)(ws + OFF_INT);
    int* cnt    = iw;
    int* eoff   = cnt + NN;        // NN+1
    int* cursor = eoff + NN + 2;
    int* esrc   = cursor + NN;
    int* ecombo = esrc + NE;

    k_zero_cnt<<<40, 256, 0, stream>>>(cnt);
    k_h0<<<640, 256, 0, stream>>>(x, node_emb, pre_lin_W, pre_lin_b, h);
    k_hist<<<625, 256, 0, stream>>>(edge_index, cnt);
    k_scan<<<1, 256, 0, stream>>>(cnt, eoff);
    k_nodestats<<<40, 256, 0, stream>>>(cnt, eoff, invdeg, amp, att, cursor);
    k_scatter<<<625, 256, 0, stream>>>(edge_index, edge_attr, cursor, esrc, ecombo);

    for (int l = 0; l < NL; l++){
        k_rlut<<<17, 128, 0, stream>>>(edge_emb, encW, encb, preW, preb, l, Rlut, stats);
        k_pq<<<313, 384, 0, stream>>>(h, preW, l, P, Q);
        k_agg<<<NN, 128, 0, stream>>>(P, Q, Rlut, eoff, esrc, ecombo, invdeg, agg);
        k_post<<<dim3(40, 5), 256, 0, stream>>>(h, agg, postW, postb, amp, att, l, post);
        k_lin<<<313, 256, 0, stream>>>(post, linW, linb, l, hc, stats);
        k_bnapply<<<2930, 256, 0, stream>>>(hc, stats, bng, bnb, l, h);
    }

    k_pool<<<NG, 256, 0, stream>>>(h, batch, gpool);
    k_mlp<<<8, 256, 0, stream>>>(gpool, mlpW1, mlpb1, mlpW2, mlpb2, mlpW3, mlpb3, (float*)d_out);
}

// Round 6
// 1362.505 us; speedup vs baseline: 1.2831x; 1.2611x over previous
//
#include <hip/hip_runtime.h>
#include <math.h>

#define NN 10000
#define NE 160000
#define NG 64
#define NT 5
#define NL 4
#define ADL 2.833213344056216f

// ws layout (float offsets)
#define OFF_H      0
#define OFF_HC     750000
#define OFF_P      1500000     // P during agg; reused as post0 [N,75] after k_agg
#define OFF_Q      5250000     // Q during agg; reused as post1/post2 after k_agg
#define OFF_AGG    9000000
#define OFF_RLUT   24000000
#define OFF_INVDEG 24006000
#define OFF_AMP    24016000
#define OFF_ATT    24026000
#define OFF_STATS  24036000
#define OFF_GPOOL  24036160
#define OFF_INT    24118960

__global__ void k_zero_cnt(int* cnt){
    int i = blockIdx.x*256 + threadIdx.x;
    if (i < NN) cnt[i] = 0;
}

// h0 = node_emb[x].reshape(N,150) @ pre_lin_W + b
__global__ __launch_bounds__(256) void k_h0(const int* __restrict__ x,
        const float* __restrict__ node_emb, const float* __restrict__ plW,
        const float* __restrict__ plb, float* __restrict__ h){
    __shared__ float s_emb[21*75];
    __shared__ float s_W[150*75];
    __shared__ float s_b[75];
    int tid = threadIdx.x;
    for (int i = tid; i < 21*75; i += 256) s_emb[i] = node_emb[i];
    for (int i = tid; i < 150*75; i += 256) s_W[i] = plW[i];
    if (tid < 75) s_b[tid] = plb[tid];
    __syncthreads();
    for (int out = blockIdx.x*256 + tid; out < NN*75; out += gridDim.x*256){
        int n = out / 75, f = out - n*75;
        int x0 = x[2*n], x1 = x[2*n+1];
        float acc = s_b[f];
        const float* e0 = s_emb + x0*75;
        const float* e1 = s_emb + x1*75;
        #pragma unroll 5
        for (int k = 0; k < 75; k++)
            acc += e0[k]*s_W[k*75+f] + e1[k]*s_W[(75+k)*75+f];
        h[out] = acc;
    }
}

__global__ void k_hist(const int* __restrict__ ei, int* __restrict__ cnt){
    int e = blockIdx.x*256 + threadIdx.x;
    if (e < NE) atomicAdd(&cnt[ei[NE + e]], 1);
}

// single-block prefix sum: eoff[0]=0, eoff[n+1]=inclusive prefix
__global__ void k_scan(const int* __restrict__ cnt, int* __restrict__ eoff){
    __shared__ int buf[256];
    __shared__ int carry;
    int tid = threadIdx.x;
    if (tid == 0){ carry = 0; eoff[0] = 0; }
    __syncthreads();
    for (int base = 0; base < NN; base += 256){
        int v = (base + tid < NN) ? cnt[base + tid] : 0;
        buf[tid] = v; __syncthreads();
        for (int off = 1; off < 256; off <<= 1){
            int t2 = (tid >= off) ? buf[tid - off] : 0;
            __syncthreads();
            buf[tid] += t2;
            __syncthreads();
        }
        int inc = buf[tid] + carry;
        if (base + tid < NN) eoff[base + tid + 1] = inc;
        __syncthreads();
        if (tid == 255) carry = inc;
        __syncthreads();
    }
}

__global__ void k_nodestats(const int* __restrict__ cnt, const int* __restrict__ eoff,
        float* __restrict__ invdeg, float* __restrict__ amp, float* __restrict__ att,
        int* __restrict__ cursor){
    int n = blockIdx.x*256 + threadIdx.x;
    if (n >= NN) return;
    int c = cnt[n];
    cursor[n] = eoff[n];
    float cf = (float)c;
    float dg = cf < 1.f ? 1.f : cf;
    invdeg[n] = 1.f / dg;
    float ld = logf(dg + 1.f);
    amp[n] = ld / ADL;
    att[n] = ADL / ld;
}

__global__ void k_scatter(const int* __restrict__ ei, const int* __restrict__ ea,
        int* __restrict__ cursor, int* __restrict__ esrc, int* __restrict__ ecombo){
    int e = blockIdx.x*256 + threadIdx.x;
    if (e >= NE) return;
    int src = ei[e], dst = ei[NE + e];
    int pos = atomicAdd(&cursor[dst], 1);
    esrc[pos] = src;
    ecombo[pos] = ea[2*e]*4 + ea[2*e+1];
}

// R_lut[combo][j] = (e-vector for combo) @ Wc + pre_b  (16x375); block 16 zeroes BN stats
__global__ void k_rlut(const float* __restrict__ edge_emb, const float* __restrict__ encW,
        const float* __restrict__ encb, const float* __restrict__ preW,
        const float* __restrict__ preb, int l, float* __restrict__ Rlut,
        float* __restrict__ stats){
    int b = blockIdx.x, tid = threadIdx.x;
    if (b == 16){
        for (int i = tid; i < 150; i += 128) stats[i] = 0.f;
        return;
    }
    int a0 = b >> 2, a1 = b & 3;
    __shared__ float ev[75];
    if (tid < 75){
        int m = tid;
        float s = encb[l*75 + m];
        for (int k = 0; k < 25; k++) s += edge_emb[a0*25+k]*encW[((size_t)l*50+k)*75+m];
        for (int k = 0; k < 25; k++) s += edge_emb[a1*25+k]*encW[((size_t)l*50+25+k)*75+m];
        ev[m] = s;
    }
    __syncthreads();
    for (int j = tid; j < 375; j += 128){
        int t = j/75, f = j - 75*t;
        float r = preb[((size_t)l*NT + t)*75 + f];
        const float* w = preW + (((size_t)(l*NT + t))*225 + 150)*75 + f;
        for (int m = 0; m < 75; m++) r += ev[m]*w[m*75];
        Rlut[b*375 + j] = r;
    }
}

// P = h @ Wa (rows 0..74 of pre_W), Q = h @ Wb (rows 75..149); [10000,75]x[75,375]
__global__ __launch_bounds__(384) void k_pq(const float* __restrict__ h,
        const float* __restrict__ preW, int l, float* __restrict__ P, float* __restrict__ Q){
    __shared__ float h_t[32*76];
    int tid = threadIdx.x;
    int base = blockIdx.x*32;
    for (int idx = tid; idx < 32*75; idx += 384){
        int i = idx/75, m = idx - 75*i;
        int n = base + i;
        h_t[i*76 + m] = (n < NN) ? h[(size_t)n*75 + m] : 0.f;
    }
    __syncthreads();
    int j = tid;
    if (j >= 375) return;
    int t = j/75, f = j - 75*t;
    const float* wbase = preW + ((size_t)(l*NT + t))*225*75 + f;
    float accP[32], accQ[32];
    #pragma unroll
    for (int i = 0; i < 32; i++){ accP[i] = 0.f; accQ[i] = 0.f; }
    for (int m = 0; m < 72; m += 4){
        float wa0 = wbase[(m+0)*75], wa1 = wbase[(m+1)*75];
        float wa2 = wbase[(m+2)*75], wa3 = wbase[(m+3)*75];
        float wb0 = wbase[(75+m+0)*75], wb1 = wbase[(75+m+1)*75];
        float wb2 = wbase[(75+m+2)*75], wb3 = wbase[(75+m+3)*75];
        #pragma unroll
        for (int i = 0; i < 32; i++){
            const float4 hv = *(const float4*)&h_t[i*76 + m];
            accP[i] += hv.x*wa0 + hv.y*wa1 + hv.z*wa2 + hv.w*wa3;
            accQ[i] += hv.x*wb0 + hv.y*wb1 + hv.z*wb2 + hv.w*wb3;
        }
    }
    for (int m = 72; m < 75; m++){
        float wa = wbase[m*75], wb = wbase[(75+m)*75];
        #pragma unroll
        for (int i = 0; i < 32; i++){
            float v = h_t[i*76 + m];
            accP[i] += v*wa; accQ[i] += v*wb;
        }
    }
    for (int i = 0; i < 32; i++){
        int n = base + i;
        if (n < NN){ P[(size_t)n*375 + j] = accP[i]; Q[(size_t)n*375 + j] = accQ[i]; }
    }
}

// one block per node: msgs[e] = P[n] + Q[src] + R_lut[combo]; sum/sumsq/min/max -> agg[N,T,300]
__global__ __launch_bounds__(128) void k_agg(const float* __restrict__ P,
        const float* __restrict__ Q, const float* __restrict__ Rlut,
        const int* __restrict__ eoff, const int* __restrict__ esrc,
        const int* __restrict__ ecombo, const float* __restrict__ invdeg,
        float* __restrict__ agg){
    int n = blockIdx.x, tid = threadIdx.x;
    int lo = eoff[n], hi = eoff[n+1];
    float p[3], sum[3] = {0,0,0}, sq[3] = {0,0,0}, mn[3], mx[3];
    #pragma unroll
    for (int c = 0; c < 3; c++){
        int j = tid + c*128;
        p[c] = (j < 375) ? P[(size_t)n*375 + j] : 0.f;
        mn[c] = 3.4e38f; mx[c] = -3.4e38f;
    }
    for (int e = lo; e < hi; e++){
        int s = esrc[e], cm = ecombo[e];
        const float* q = Q + (size_t)s*375;
        const float* r = Rlut + cm*375;
        #pragma unroll
        for (int c = 0; c < 3; c++){
            int j = tid + c*128;
            if (j < 375){
                float m = p[c] + q[j] + r[j];
                sum[c] += m; sq[c] += m*m;
                mn[c] = fminf(mn[c], m); mx[c] = fmaxf(mx[c], m);
            }
        }
    }
    float id = invdeg[n];
    bool has = hi > lo;
    #pragma unroll
    for (int c = 0; c < 3; c++){
        int j = tid + c*128;
        if (j >= 375) continue;
        float mean = sum[c]*id;
        float msq  = sq[c]*id;
        float var = msq - mean*mean; var = var > 0.f ? var : 0.f;
        float sd = sqrtf(var + 1e-5f);
        float mnv = has ? mn[c] : 0.f;
        float mxv = has ? mx[c] : 0.f;
        int t = j/75, f = j - 75*t;
        float* a = agg + ((size_t)n*NT + t)*300;
        a[f] = mean; a[75+f] = mnv; a[150+f] = mxv; a[225+f] = sd;
    }
}

// post einsum, LDS-tiled + k-split over blockIdx.z for occupancy.
// block = 256 nodes x 1 tower x 1 k-range; thread = (sub, fgroup) x 4 nodes.
// z0: h-part + agg k [0,100) (+bias); z1: agg [100,200); z2: agg [200,300).
// grid (40, 5, 3). Partials summed in k_lin (linearity).
#define TK 25
#define PADA 27
__global__ __launch_bounds__(256, 4) void k_post(const float* __restrict__ h,
        const float* __restrict__ agg, const float* __restrict__ postW,
        const float* __restrict__ postb, const float* __restrict__ amp,
        const float* __restrict__ att, int l,
        float* __restrict__ post0, float* __restrict__ post1, float* __restrict__ post2){
    __shared__ float s_a[256*PADA];      // 27.6 KB activation tile
    __shared__ float s_w[3][TK*16];      // 4.8 KB weight tiles (f padded to 16)
    int t = blockIdx.y;
    int z = blockIdx.z;
    int nbase = blockIdx.x*256;
    int tid = threadIdx.x;
    int fg  = (tid & 3)*4;
    int sub = tid >> 2;
    const float* Wt = postW + ((size_t)(l*NT + t))*975*15;
    float a1[4][4], a2[4][4], a3[4][4];
    #pragma unroll
    for (int j = 0; j < 4; j++)
        #pragma unroll
        for (int f = 0; f < 4; f++){ a1[j][f]=0.f; a2[j][f]=0.f; a3[j][f]=0.f; }

    // ---- h-part (z==0 only): k = 0..74, weight rows 0..74, accumulates into a1 ----
    if (z == 0){
        for (int kt = 0; kt < 75; kt += TK){
            for (int idx = tid; idx < 256*TK; idx += 256){
                int row = idx / TK, c = idx - row*TK;
                int n = nbase + row;
                s_a[row*PADA + c] = (n < NN) ? h[(size_t)n*75 + kt + c] : 0.f;
            }
            for (int idx = tid; idx < TK*16; idx += 256){
                int c = idx >> 4, f = idx & 15;
                s_w[0][idx] = (f < 15) ? Wt[(kt + c)*15 + f] : 0.f;
            }
            __syncthreads();
            for (int k = 0; k < TK; k++){
                const float4 w1 = *(const float4*)&s_w[0][k*16 + fg];
                #pragma unroll
                for (int j = 0; j < 4; j++){
                    float v = s_a[(sub + 64*j)*PADA + k];
                    a1[j][0] += v*w1.x; a1[j][1] += v*w1.y;
                    a1[j][2] += v*w1.z; a1[j][3] += v*w1.w;
                }
            }
            __syncthreads();
        }
    }

    // ---- agg part: k in [z*100, z*100+100); rows 75+k / 375+k / 675+k ----
    int kbeg = z*100, kend = kbeg + 100;
    for (int kt = kbeg; kt < kend; kt += TK){
        for (int idx = tid; idx < 256*TK; idx += 256){
            int row = idx / TK, c = idx - row*TK;
            int n = nbase + row;
            s_a[row*PADA + c] = (n < NN) ? agg[(size_t)n*1500 + t*300 + kt + c] : 0.f;
        }
        for (int idx = tid; idx < TK*16; idx += 256){
            int c = idx >> 4, f = idx & 15;
            float v1 = 0.f, v2 = 0.f, v3 = 0.f;
            if (f < 15){
                v1 = Wt[( 75 + kt + c)*15 + f];
                v2 = Wt[(375 + kt + c)*15 + f];
                v3 = Wt[(675 + kt + c)*15 + f];
            }
            s_w[0][idx] = v1; s_w[1][idx] = v2; s_w[2][idx] = v3;
        }
        __syncthreads();
        for (int k = 0; k < TK; k++){
            const float4 w1 = *(const float4*)&s_w[0][k*16 + fg];
            const float4 w2 = *(const float4*)&s_w[1][k*16 + fg];
            const float4 w3 = *(const float4*)&s_w[2][k*16 + fg];
            #pragma unroll
            for (int j = 0; j < 4; j++){
                float v = s_a[(sub + 64*j)*PADA + k];
                a1[j][0] += v*w1.x; a1[j][1] += v*w1.y;
                a1[j][2] += v*w1.z; a1[j][3] += v*w1.w;
                a2[j][0] += v*w2.x; a2[j][1] += v*w2.y;
                a2[j][2] += v*w2.z; a2[j][3] += v*w2.w;
                a3[j][0] += v*w3.x; a3[j][1] += v*w3.y;
                a3[j][2] += v*w3.z; a3[j][3] += v*w3.w;
            }
        }
        __syncthreads();
    }

    float* postv = (z == 0) ? post0 : ((z == 1) ? post1 : post2);
    const float* pb = postb + (l*NT + t)*15;
    #pragma unroll
    for (int j = 0; j < 4; j++){
        int n = nbase + sub + 64*j;
        if (n >= NN) continue;
        float am = amp[n], at = att[n];
        float* dst = postv + (size_t)n*75 + t*15;
        #pragma unroll
        for (int f = 0; f < 4; f++){
            if (fg + f < 15){
                float r = a1[j][f] + am*a2[j][f] + at*a3[j][f];
                if (z == 0) r += pb[fg + f];
                dst[fg + f] = r;
            }
        }
    }
}

// hc = (post0+post1+post2) @ lin_W[l] + lin_b[l]; fused per-block BN-stat reduction
__global__ __launch_bounds__(256) void k_lin(const float* __restrict__ post0,
        const float* __restrict__ post1, const float* __restrict__ post2,
        const float* __restrict__ linW, const float* __restrict__ linb,
        int l, float* __restrict__ hc, float* __restrict__ stats){
    __shared__ float p_l[32*75];
    __shared__ float w_l[75*75];
    __shared__ float hc_l[32*75];
    int tid = threadIdx.x;
    int base = blockIdx.x*32;
    for (int i = tid; i < 75*75; i += 256) w_l[i] = linW[(size_t)l*5625 + i];
    for (int i = tid; i < 32*75; i += 256){
        int n = base + i/75;
        size_t idx = (size_t)base*75 + i;
        p_l[i] = (n < NN) ? (post0[idx] + post1[idx] + post2[idx]) : 0.f;
    }
    __syncthreads();
    for (int task = tid; task < 2400; task += 256){
        int i = task/75, o = task - 75*i;
        float s = linb[l*75 + o];
        const float* pl = p_l + i*75;
        #pragma unroll 5
        for (int j = 0; j < 75; j++) s += pl[j]*w_l[j*75 + o];
        hc_l[task] = s;
        if (base + i < NN) hc[(size_t)(base+i)*75 + o] = s;
    }
    __syncthreads();
    if (tid < 75){
        int nv = NN - base; if (nv > 32) nv = 32;
        float s1 = 0.f, s2 = 0.f;
        for (int i = 0; i < nv; i++){
            float v = hc_l[i*75 + tid];
            s1 += v; s2 += v*v;
        }
        atomicAdd(&stats[tid], s1);
        atomicAdd(&stats[75+tid], s2);
    }
}

__global__ void k_bnapply(const float* __restrict__ hc, const float* __restrict__ stats,
        const float* __restrict__ bng, const float* __restrict__ bnb, int l,
        float* __restrict__ h){
    int idx = blockIdx.x*256 + threadIdx.x;
    if (idx >= NN*75) return;
    int col = idx % 75;
    float mu = stats[col]*(1.0f/NN);
    float var = stats[75+col]*(1.0f/NN) - mu*mu;
    float inv = rsqrtf(var + 1e-5f);
    float v = (hc[idx] - mu)*inv*bng[l*75+col] + bnb[l*75+col];
    h[idx] = v > 0.f ? v : 0.f;
}

__global__ __launch_bounds__(256) void k_pool(const float* __restrict__ h,
        const int* __restrict__ batch, float* __restrict__ gpool){
    int g = blockIdx.x, tid = threadIdx.x;
    int lo = 0, hi = NN;
    while (lo < hi){ int mid = (lo+hi)>>1; if (batch[mid] < g) lo = mid+1; else hi = mid; }
    int start = lo;
    lo = start; hi = NN;
    while (lo < hi){ int mid = (lo+hi)>>1; if (batch[mid] < g+1) lo = mid+1; else hi = mid; }
    int end = lo;
    __shared__ float red[225];
    if (tid < 225){
        int col = tid % 75, rep = tid / 75;
        float acc = 0.f;
        for (int i = start + rep; i < end; i += 3) acc += h[(size_t)i*75 + col];
        red[tid] = acc;
    }
    __syncthreads();
    if (tid < 75) gpool[g*75 + tid] = red[tid] + red[75+tid] + red[150+tid];
}

// 8 blocks x 8 graphs; weights in LDS, phase-parallel
__global__ __launch_bounds__(256) void k_mlp(const float* __restrict__ gpool,
        const float* __restrict__ W1, const float* __restrict__ b1,
        const float* __restrict__ W2, const float* __restrict__ b2,
        const float* __restrict__ W3, const float* __restrict__ b3,
        float* __restrict__ out){
    __shared__ float w1[75*50];
    __shared__ float w2[50*25];
    __shared__ float gp[8*75];
    __shared__ float t1[8*50];
    __shared__ float t2[8*25];
    int tid = threadIdx.x;
    int gbase = blockIdx.x*8;
    for (int i = tid; i < 75*50; i += 256) w1[i] = W1[i];
    for (int i = tid; i < 50*25; i += 256) w2[i] = W2[i];
    for (int i = tid; i < 8*75; i += 256) gp[i] = gpool[gbase*75 + i];
    __syncthreads();
    for (int task = tid; task < 8*50; task += 256){
        int g = task/50, j = task - 50*g;
        float s = b1[j];
        const float* gv = gp + g*75;
        #pragma unroll 5
        for (int k = 0; k < 75; k++) s += gv[k]*w1[k*50+j];
        t1[task] = s > 0.f ? s : 0.f;
    }
    __syncthreads();
    for (int task = tid; task < 8*25; task += 256){
        int g = task/25, j = task - 25*g;
        float s = b2[j];
        const float* tv = t1 + g*50;
        #pragma unroll 5
        for (int k = 0; k < 50; k++) s += tv[k]*w2[k*25+j];
        t2[task] = s > 0.f ? s : 0.f;
    }
    __syncthreads();
    if (tid < 8){
        float s = b3[0];
        const float* tv = t2 + tid*25;
        #pragma unroll
        for (int k = 0; k < 25; k++) s += tv[k]*W3[k];
        out[gbase + tid] = s;
    }
}

extern "C" void kernel_launch(void* const* d_in, const int* in_sizes, int n_in,
                              void* d_out, int out_size, void* d_ws, size_t ws_size,
                              hipStream_t stream){
    const int* x          = (const int*)d_in[0];
    const int* edge_index = (const int*)d_in[1];
    const int* edge_attr  = (const int*)d_in[2];
    const int* batch      = (const int*)d_in[3];
    const float* node_emb = (const float*)d_in[4];
    const float* edge_emb = (const float*)d_in[5];
    const float* pre_lin_W= (const float*)d_in[6];
    const float* pre_lin_b= (const float*)d_in[7];
    const float* encW     = (const float*)d_in[8];
    const float* encb     = (const float*)d_in[9];
    const float* preW     = (const float*)d_in[10];
    const float* preb     = (const float*)d_in[11];
    const float* postW    = (const float*)d_in[12];
    const float* postb    = (const float*)d_in[13];
    const float* linW     = (const float*)d_in[14];
    const float* linb     = (const float*)d_in[15];
    const float* bng      = (const float*)d_in[16];
    const float* bnb      = (const float*)d_in[17];
    const float* mlpW1    = (const float*)d_in[18];
    const float* mlpb1    = (const float*)d_in[19];
    const float* mlpW2    = (const float*)d_in[20];
    const float* mlpb2    = (const float*)d_in[21];
    const float* mlpW3    = (const float*)d_in[22];
    const float* mlpb3    = (const float*)d_in[23];

    float* ws = (float*)d_ws;
    float* h      = ws + OFF_H;
    float* hc     = ws + OFF_HC;
    float* P      = ws + OFF_P;
    float* Q      = ws + OFF_Q;
    float* agg    = ws + OFF_AGG;
    float* Rlut   = ws + OFF_RLUT;
    float* invdeg = ws + OFF_INVDEG;
    float* amp    = ws + OFF_AMP;
    float* att    = ws + OFF_ATT;
    float* stats  = ws + OFF_STATS;
    float* gpool  = ws + OFF_GPOOL;
    float* post0  = ws + OFF_P;            // reuses P region (P dead after k_agg)
    float* post1  = ws + OFF_Q;            // reuses Q region (Q dead after k_agg)
    float* post2  = ws + OFF_Q + 750000;
    int* iw     = (int*)(ws + OFF_INT);
    int* cnt    = iw;
    int* eoff   = cnt + NN;        // NN+1
    int* cursor = eoff + NN + 2;
    int* esrc   = cursor + NN;
    int* ecombo = esrc + NE;

    k_zero_cnt<<<40, 256, 0, stream>>>(cnt);
    k_h0<<<640, 256, 0, stream>>>(x, node_emb, pre_lin_W, pre_lin_b, h);
    k_hist<<<625, 256, 0, stream>>>(edge_index, cnt);
    k_scan<<<1, 256, 0, stream>>>(cnt, eoff);
    k_nodestats<<<40, 256, 0, stream>>>(cnt, eoff, invdeg, amp, att, cursor);
    k_scatter<<<625, 256, 0, stream>>>(edge_index, edge_attr, cursor, esrc, ecombo);

    for (int l = 0; l < NL; l++){
        k_rlut<<<17, 128, 0, stream>>>(edge_emb, encW, encb, preW, preb, l, Rlut, stats);
        k_pq<<<313, 384, 0, stream>>>(h, preW, l, P, Q);
        k_agg<<<NN, 128, 0, stream>>>(P, Q, Rlut, eoff, esrc, ecombo, invdeg, agg);
        k_post<<<dim3(40, 5, 3), 256, 0, stream>>>(h, agg, postW, postb, amp, att, l,
                                                   post0, post1, post2);
        k_lin<<<313, 256, 0, stream>>>(post0, post1, post2, linW, linb, l, hc, stats);
        k_bnapply<<<2930, 256, 0, stream>>>(hc, stats, bng, bnb, l, h);
    }

    k_pool<<<NG, 256, 0, stream>>>(h, batch, gpool);
    k_mlp<<<8, 256, 0, stream>>>(gpool, mlpW1, mlpb1, mlpW2, mlpb2, mlpW3, mlpb3, (float*)d_out);
}

// Round 7
// 1045.360 us; speedup vs baseline: 1.6723x; 1.3034x over previous
//
#include <hip/hip_runtime.h>
#include <math.h>

#define NN 10000
#define NE 160000
#define NG 64
#define NT 5
#define NL 4
#define ADL 2.833213344056216f

// ws layout (float offsets)
#define OFF_H      0
#define OFF_HC     750000
#define OFF_P      1500000     // P during agg; reused as post0..post3 after k_agg
#define OFF_Q      5250000
#define OFF_AGG    9000000
#define OFF_RLUT   24000000
#define OFF_INVDEG 24006000
#define OFF_AMP    24016000
#define OFF_ATT    24026000
#define OFF_STATS  24036000
#define OFF_GPOOL  24036160
#define OFF_INT    24118960

__global__ void k_zero_cnt(int* cnt){
    int i = blockIdx.x*256 + threadIdx.x;
    if (i < NN) cnt[i] = 0;
}

// h0 = node_emb[x].reshape(N,150) @ pre_lin_W + b
__global__ __launch_bounds__(256) void k_h0(const int* __restrict__ x,
        const float* __restrict__ node_emb, const float* __restrict__ plW,
        const float* __restrict__ plb, float* __restrict__ h){
    __shared__ float s_emb[21*75];
    __shared__ float s_W[150*75];
    __shared__ float s_b[75];
    int tid = threadIdx.x;
    for (int i = tid; i < 21*75; i += 256) s_emb[i] = node_emb[i];
    for (int i = tid; i < 150*75; i += 256) s_W[i] = plW[i];
    if (tid < 75) s_b[tid] = plb[tid];
    __syncthreads();
    for (int out = blockIdx.x*256 + tid; out < NN*75; out += gridDim.x*256){
        int n = out / 75, f = out - n*75;
        int x0 = x[2*n], x1 = x[2*n+1];
        float acc = s_b[f];
        const float* e0 = s_emb + x0*75;
        const float* e1 = s_emb + x1*75;
        #pragma unroll 5
        for (int k = 0; k < 75; k++)
            acc += e0[k]*s_W[k*75+f] + e1[k]*s_W[(75+k)*75+f];
        h[out] = acc;
    }
}

__global__ void k_hist(const int* __restrict__ ei, int* __restrict__ cnt){
    int e = blockIdx.x*256 + threadIdx.x;
    if (e < NE) atomicAdd(&cnt[ei[NE + e]], 1);
}

// single-block prefix sum: eoff[0]=0, eoff[n+1]=inclusive prefix
__global__ void k_scan(const int* __restrict__ cnt, int* __restrict__ eoff){
    __shared__ int buf[256];
    __shared__ int carry;
    int tid = threadIdx.x;
    if (tid == 0){ carry = 0; eoff[0] = 0; }
    __syncthreads();
    for (int base = 0; base < NN; base += 256){
        int v = (base + tid < NN) ? cnt[base + tid] : 0;
        buf[tid] = v; __syncthreads();
        for (int off = 1; off < 256; off <<= 1){
            int t2 = (tid >= off) ? buf[tid - off] : 0;
            __syncthreads();
            buf[tid] += t2;
            __syncthreads();
        }
        int inc = buf[tid] + carry;
        if (base + tid < NN) eoff[base + tid + 1] = inc;
        __syncthreads();
        if (tid == 255) carry = inc;
        __syncthreads();
    }
}

__global__ void k_nodestats(const int* __restrict__ cnt, const int* __restrict__ eoff,
        float* __restrict__ invdeg, float* __restrict__ amp, float* __restrict__ att,
        int* __restrict__ cursor){
    int n = blockIdx.x*256 + threadIdx.x;
    if (n >= NN) return;
    int c = cnt[n];
    cursor[n] = eoff[n];
    float cf = (float)c;
    float dg = cf < 1.f ? 1.f : cf;
    invdeg[n] = 1.f / dg;
    float ld = logf(dg + 1.f);
    amp[n] = ld / ADL;
    att[n] = ADL / ld;
}

__global__ void k_scatter(const int* __restrict__ ei, const int* __restrict__ ea,
        int* __restrict__ cursor, int* __restrict__ esrc, int* __restrict__ ecombo){
    int e = blockIdx.x*256 + threadIdx.x;
    if (e >= NE) return;
    int src = ei[e], dst = ei[NE + e];
    int pos = atomicAdd(&cursor[dst], 1);
    esrc[pos] = src;
    ecombo[pos] = ea[2*e]*4 + ea[2*e+1];
}

// Fused kernel, grid 319 x 384:
//  bx <  313 : P = h @ Wa, Q = h @ Wb  (32 nodes/block)
//  bx 313-317: Rlut for tower t = bx-313 (LDS-staged encW/ev/Wc, coalesced)
//  bx == 318 : zero BN stats
__global__ __launch_bounds__(384) void k_pq(const float* __restrict__ h,
        const float* __restrict__ preW, const float* __restrict__ preb,
        const float* __restrict__ edge_emb, const float* __restrict__ encW,
        const float* __restrict__ encb, int l,
        float* __restrict__ P, float* __restrict__ Q,
        float* __restrict__ Rlut, float* __restrict__ stats){
    __shared__ float smem[10675];
    int tid = threadIdx.x;
    int bx = blockIdx.x;

    if (bx == 318){
        for (int i = tid; i < 150; i += 384) stats[i] = 0.f;
        return;
    }
    if (bx >= 313){
        // ---- Rlut for tower t ----
        int t = bx - 313;
        float* s_encW = smem;            // 50*75 = 3750
        float* s_ev   = smem + 3750;     // 16*75 = 1200
        float* s_wc   = smem + 4950;     // 75*75 = 5625
        float* s_ee   = smem + 10575;    // 100
        for (int i = tid; i < 3750; i += 384) s_encW[i] = encW[(size_t)l*3750 + i];
        for (int i = tid; i < 100; i += 384) s_ee[i] = edge_emb[i];
        const float* wcsrc = preW + (((size_t)(l*NT + t))*225 + 150)*75;
        for (int i = tid; i < 5625; i += 384) s_wc[i] = wcsrc[i];
        __syncthreads();
        for (int task = tid; task < 1200; task += 384){
            int b = task/75, m = task - 75*b;
            int a0 = b >> 2, a1 = b & 3;
            float s = encb[l*75 + m];
            for (int k = 0; k < 25; k++)
                s += s_ee[a0*25+k]*s_encW[k*75+m] + s_ee[a1*25+k]*s_encW[(25+k)*75+m];
            s_ev[task] = s;
        }
        __syncthreads();
        for (int task = tid; task < 1200; task += 384){
            int b = task/75, f = task - 75*b;
            float r = preb[((size_t)l*NT + t)*75 + f];
            const float* ev = s_ev + b*75;
            #pragma unroll 5
            for (int m = 0; m < 75; m++) r += ev[m]*s_wc[m*75 + f];
            Rlut[b*375 + t*75 + f] = r;
        }
        return;
    }

    // ---- P/Q ----
    float* h_t = smem;   // 32*76 = 2432
    int base = bx*32;
    for (int idx = tid; idx < 32*75; idx += 384){
        int i = idx/75, m = idx - 75*i;
        int n = base + i;
        h_t[i*76 + m] = (n < NN) ? h[(size_t)n*75 + m] : 0.f;
    }
    __syncthreads();
    int j = tid;
    if (j >= 375) return;
    int t = j/75, f = j - 75*t;
    const float* wbase = preW + ((size_t)(l*NT + t))*225*75 + f;
    float accP[32], accQ[32];
    #pragma unroll
    for (int i = 0; i < 32; i++){ accP[i] = 0.f; accQ[i] = 0.f; }
    for (int m = 0; m < 72; m += 4){
        float wa0 = wbase[(m+0)*75], wa1 = wbase[(m+1)*75];
        float wa2 = wbase[(m+2)*75], wa3 = wbase[(m+3)*75];
        float wb0 = wbase[(75+m+0)*75], wb1 = wbase[(75+m+1)*75];
        float wb2 = wbase[(75+m+2)*75], wb3 = wbase[(75+m+3)*75];
        #pragma unroll
        for (int i = 0; i < 32; i++){
            const float4 hv = *(const float4*)&h_t[i*76 + m];
            accP[i] += hv.x*wa0 + hv.y*wa1 + hv.z*wa2 + hv.w*wa3;
            accQ[i] += hv.x*wb0 + hv.y*wb1 + hv.z*wb2 + hv.w*wb3;
        }
    }
    for (int m = 72; m < 75; m++){
        float wa = wbase[m*75], wb = wbase[(75+m)*75];
        #pragma unroll
        for (int i = 0; i < 32; i++){
            float v = h_t[i*76 + m];
            accP[i] += v*wa; accQ[i] += v*wb;
        }
    }
    for (int i = 0; i < 32; i++){
        int n = base + i;
        if (n < NN){ P[(size_t)n*375 + j] = accP[i]; Q[(size_t)n*375 + j] = accQ[i]; }
    }
}

// grid (NN, 2), block 192: y covers j in [y*192, y*192+192) ∩ [0,375)
__global__ __launch_bounds__(192) void k_agg(const float* __restrict__ P,
        const float* __restrict__ Q, const float* __restrict__ Rlut,
        const int* __restrict__ eoff, const int* __restrict__ esrc,
        const int* __restrict__ ecombo, const float* __restrict__ invdeg,
        float* __restrict__ agg){
    int n = blockIdx.x;
    int j = blockIdx.y*192 + threadIdx.x;
    if (j >= 375) return;
    int lo = eoff[n], hi = eoff[n+1];
    float p = P[(size_t)n*375 + j];
    float sum = 0.f, sq = 0.f, mn = 3.4e38f, mx = -3.4e38f;
    for (int e = lo; e < hi; e++){
        int s = esrc[e], cm = ecombo[e];
        float m = p + Q[(size_t)s*375 + j] + Rlut[cm*375 + j];
        sum += m; sq += m*m;
        mn = fminf(mn, m); mx = fmaxf(mx, m);
    }
    float id = invdeg[n];
    bool has = hi > lo;
    float mean = sum*id;
    float msq  = sq*id;
    float var = msq - mean*mean; var = var > 0.f ? var : 0.f;
    float sd = sqrtf(var + 1e-5f);
    float mnv = has ? mn : 0.f;
    float mxv = has ? mx : 0.f;
    int t = j/75, f = j - 75*t;
    float* a = agg + ((size_t)n*NT + t)*300;
    a[f] = mean; a[75+f] = mnv; a[150+f] = mxv; a[225+f] = sd;
}

// post einsum, LDS-tiled + 4-way k-split over blockIdx.z.
// z0: h-part (3 tiles, +bias, a1 only); z1..z3: 4 agg tiles each.
// grid (40, 5, 4). Partials summed in k_lin.
#define TK 25
#define PADA 27
__global__ __launch_bounds__(256, 4) void k_post(const float* __restrict__ h,
        const float* __restrict__ agg, const float* __restrict__ postW,
        const float* __restrict__ postb, const float* __restrict__ amp,
        const float* __restrict__ att, int l, float* __restrict__ postbase){
    __shared__ float s_a[256*PADA];      // 27.6 KB activation tile
    __shared__ float s_w[3][TK*16];      // 4.8 KB weight tiles (f padded to 16)
    int t = blockIdx.y;
    int z = blockIdx.z;
    int nbase = blockIdx.x*256;
    int tid = threadIdx.x;
    int fg  = (tid & 3)*4;
    int sub = tid >> 2;
    const float* Wt = postW + ((size_t)(l*NT + t))*975*15;
    float a1[4][4], a2[4][4], a3[4][4];
    #pragma unroll
    for (int j = 0; j < 4; j++)
        #pragma unroll
        for (int f = 0; f < 4; f++){ a1[j][f]=0.f; a2[j][f]=0.f; a3[j][f]=0.f; }

    if (z == 0){
        // ---- h-part: k = 0..74, weight rows 0..74, a1 only ----
        for (int kt = 0; kt < 75; kt += TK){
            for (int idx = tid; idx < 256*TK; idx += 256){
                int row = idx / TK, c = idx - row*TK;
                int n = nbase + row;
                s_a[row*PADA + c] = (n < NN) ? h[(size_t)n*75 + kt + c] : 0.f;
            }
            for (int idx = tid; idx < TK*16; idx += 256){
                int c = idx >> 4, f = idx & 15;
                s_w[0][idx] = (f < 15) ? Wt[(kt + c)*15 + f] : 0.f;
            }
            __syncthreads();
            for (int k = 0; k < TK; k++){
                const float4 w1 = *(const float4*)&s_w[0][k*16 + fg];
                #pragma unroll
                for (int j = 0; j < 4; j++){
                    float v = s_a[(sub + 64*j)*PADA + k];
                    a1[j][0] += v*w1.x; a1[j][1] += v*w1.y;
                    a1[j][2] += v*w1.z; a1[j][3] += v*w1.w;
                }
            }
            __syncthreads();
        }
        float* postv = postbase;   // z slice 0
        const float* pb = postb + (l*NT + t)*15;
        #pragma unroll
        for (int j = 0; j < 4; j++){
            int n = nbase + sub + 64*j;
            if (n >= NN) continue;
            float* dst = postv + (size_t)n*75 + t*15;
            #pragma unroll
            for (int f = 0; f < 4; f++)
                if (fg + f < 15) dst[fg + f] = a1[j][f] + pb[fg + f];
        }
        return;
    }

    // ---- agg part: 4 tiles, k in [(z-1)*100, (z-1)*100+100) ----
    int kbeg = (z-1)*100, kend = kbeg + 100;
    for (int kt = kbeg; kt < kend; kt += TK){
        for (int idx = tid; idx < 256*TK; idx += 256){
            int row = idx / TK, c = idx - row*TK;
            int n = nbase + row;
            s_a[row*PADA + c] = (n < NN) ? agg[(size_t)n*1500 + t*300 + kt + c] : 0.f;
        }
        for (int idx = tid; idx < TK*16; idx += 256){
            int c = idx >> 4, f = idx & 15;
            float v1 = 0.f, v2 = 0.f, v3 = 0.f;
            if (f < 15){
                v1 = Wt[( 75 + kt + c)*15 + f];
                v2 = Wt[(375 + kt + c)*15 + f];
                v3 = Wt[(675 + kt + c)*15 + f];
            }
            s_w[0][idx] = v1; s_w[1][idx] = v2; s_w[2][idx] = v3;
        }
        __syncthreads();
        for (int k = 0; k < TK; k++){
            const float4 w1 = *(const float4*)&s_w[0][k*16 + fg];
            const float4 w2 = *(const float4*)&s_w[1][k*16 + fg];
            const float4 w3 = *(const float4*)&s_w[2][k*16 + fg];
            #pragma unroll
            for (int j = 0; j < 4; j++){
                float v = s_a[(sub + 64*j)*PADA + k];
                a1[j][0] += v*w1.x; a1[j][1] += v*w1.y;
                a1[j][2] += v*w1.z; a1[j][3] += v*w1.w;
                a2[j][0] += v*w2.x; a2[j][1] += v*w2.y;
                a2[j][2] += v*w2.z; a2[j][3] += v*w2.w;
                a3[j][0] += v*w3.x; a3[j][1] += v*w3.y;
                a3[j][2] += v*w3.z; a3[j][3] += v*w3.w;
            }
        }
        __syncthreads();
    }

    float* postv = postbase + (size_t)z*750000;
    #pragma unroll
    for (int j = 0; j < 4; j++){
        int n = nbase + sub + 64*j;
        if (n >= NN) continue;
        float am = amp[n], at = att[n];
        float* dst = postv + (size_t)n*75 + t*15;
        #pragma unroll
        for (int f = 0; f < 4; f++)
            if (fg + f < 15)
                dst[fg + f] = a1[j][f] + am*a2[j][f] + at*a3[j][f];
    }
}

// hc = (Σz postz) @ lin_W[l] + lin_b[l]; fused per-block BN-stat reduction
__global__ __launch_bounds__(256) void k_lin(const float* __restrict__ postbase,
        const float* __restrict__ linW, const float* __restrict__ linb,
        int l, float* __restrict__ hc, float* __restrict__ stats){
    __shared__ float p_l[32*75];
    __shared__ float w_l[75*75];
    __shared__ float hc_l[32*75];
    int tid = threadIdx.x;
    int base = blockIdx.x*32;
    for (int i = tid; i < 75*75; i += 256) w_l[i] = linW[(size_t)l*5625 + i];
    for (int i = tid; i < 32*75; i += 256){
        int n = base + i/75;
        size_t idx = (size_t)base*75 + i;
        p_l[i] = (n < NN) ? (postbase[idx] + postbase[idx+750000]
                           + postbase[idx+1500000] + postbase[idx+2250000]) : 0.f;
    }
    __syncthreads();
    for (int task = tid; task < 2400; task += 256){
        int i = task/75, o = task - 75*i;
        float s = linb[l*75 + o];
        const float* pl = p_l + i*75;
        #pragma unroll 5
        for (int j = 0; j < 75; j++) s += pl[j]*w_l[j*75 + o];
        hc_l[task] = s;
        if (base + i < NN) hc[(size_t)(base+i)*75 + o] = s;
    }
    __syncthreads();
    if (tid < 75){
        int nv = NN - base; if (nv > 32) nv = 32;
        float s1 = 0.f, s2 = 0.f;
        for (int i = 0; i < nv; i++){
            float v = hc_l[i*75 + tid];
            s1 += v; s2 += v*v;
        }
        atomicAdd(&stats[tid], s1);
        atomicAdd(&stats[75+tid], s2);
    }
}

__global__ void k_bnapply(const float* __restrict__ hc, const float* __restrict__ stats,
        const float* __restrict__ bng, const float* __restrict__ bnb, int l,
        float* __restrict__ h){
    int idx = blockIdx.x*256 + threadIdx.x;
    if (idx >= NN*75) return;
    int col = idx % 75;
    float mu = stats[col]*(1.0f/NN);
    float var = stats[75+col]*(1.0f/NN) - mu*mu;
    float inv = rsqrtf(var + 1e-5f);
    float v = (hc[idx] - mu)*inv*bng[l*75+col] + bnb[l*75+col];
    h[idx] = v > 0.f ? v : 0.f;
}

__global__ __launch_bounds__(256) void k_pool(const float* __restrict__ h,
        const int* __restrict__ batch, float* __restrict__ gpool){
    int g = blockIdx.x, tid = threadIdx.x;
    int lo = 0, hi = NN;
    while (lo < hi){ int mid = (lo+hi)>>1; if (batch[mid] < g) lo = mid+1; else hi = mid; }
    int start = lo;
    lo = start; hi = NN;
    while (lo < hi){ int mid = (lo+hi)>>1; if (batch[mid] < g+1) lo = mid+1; else hi = mid; }
    int end = lo;
    __shared__ float red[225];
    if (tid < 225){
        int col = tid % 75, rep = tid / 75;
        float acc = 0.f;
        for (int i = start + rep; i < end; i += 3) acc += h[(size_t)i*75 + col];
        red[tid] = acc;
    }
    __syncthreads();
    if (tid < 75) gpool[g*75 + tid] = red[tid] + red[75+tid] + red[150+tid];
}

// 8 blocks x 8 graphs; weights in LDS, phase-parallel
__global__ __launch_bounds__(256) void k_mlp(const float* __restrict__ gpool,
        const float* __restrict__ W1, const float* __restrict__ b1,
        const float* __restrict__ W2, const float* __restrict__ b2,
        const float* __restrict__ W3, const float* __restrict__ b3,
        float* __restrict__ out){
    __shared__ float w1[75*50];
    __shared__ float w2[50*25];
    __shared__ float gp[8*75];
    __shared__ float t1[8*50];
    __shared__ float t2[8*25];
    int tid = threadIdx.x;
    int gbase = blockIdx.x*8;
    for (int i = tid; i < 75*50; i += 256) w1[i] = W1[i];
    for (int i = tid; i < 50*25; i += 256) w2[i] = W2[i];
    for (int i = tid; i < 8*75; i += 256) gp[i] = gpool[gbase*75 + i];
    __syncthreads();
    for (int task = tid; task < 8*50; task += 256){
        int g = task/50, j = task - 50*g;
        float s = b1[j];
        const float* gv = gp + g*75;
        #pragma unroll 5
        for (int k = 0; k < 75; k++) s += gv[k]*w1[k*50+j];
        t1[task] = s > 0.f ? s : 0.f;
    }
    __syncthreads();
    for (int task = tid; task < 8*25; task += 256){
        int g = task/25, j = task - 25*g;
        float s = b2[j];
        const float* tv = t1 + g*50;
        #pragma unroll 5
        for (int k = 0; k < 50; k++) s += tv[k]*w2[k*25+j];
        t2[task] = s > 0.f ? s : 0.f;
    }
    __syncthreads();
    if (tid < 8){
        float s = b3[0];
        const float* tv = t2 + tid*25;
        #pragma unroll
        for (int k = 0; k < 25; k++) s += tv[k]*W3[k];
        out[gbase + tid] = s;
    }
}

extern "C" void kernel_launch(void* const* d_in, const int* in_sizes, int n_in,
                              void* d_out, int out_size, void* d_ws, size_t ws_size,
                              hipStream_t stream){
    const int* x          = (const int*)d_in[0];
    const int* edge_index = (const int*)d_in[1];
    const int* edge_attr  = (const int*)d_in[2];
    const int* batch      = (const int*)d_in[3];
    const float* node_emb = (const float*)d_in[4];
    const float* edge_emb = (const float*)d_in[5];
    const float* pre_lin_W= (const float*)d_in[6];
    const float* pre_lin_b= (const float*)d_in[7];
    const float* encW     = (const float*)d_in[8];
    const float* encb     = (const float*)d_in[9];
    const float* preW     = (const float*)d_in[10];
    const float* preb     = (const float*)d_in[11];
    const float* postW    = (const float*)d_in[12];
    const float* postb    = (const float*)d_in[13];
    const float* linW     = (const float*)d_in[14];
    const float* linb     = (const float*)d_in[15];
    const float* bng      = (const float*)d_in[16];
    const float* bnb      = (const float*)d_in[17];
    const float* mlpW1    = (const float*)d_in[18];
    const float* mlpb1    = (const float*)d_in[19];
    const float* mlpW2    = (const float*)d_in[20];
    const float* mlpb2    = (const float*)d_in[21];
    const float* mlpW3    = (const float*)d_in[22];
    const float* mlpb3    = (const float*)d_in[23];

    float* ws = (float*)d_ws;
    float* h      = ws + OFF_H;
    float* hc     = ws + OFF_HC;
    float* P      = ws + OFF_P;
    float* Q      = ws + OFF_Q;
    float* agg    = ws + OFF_AGG;
    float* Rlut   = ws + OFF_RLUT;
    float* invdeg = ws + OFF_INVDEG;
    float* amp    = ws + OFF_AMP;
    float* att    = ws + OFF_ATT;
    float* stats  = ws + OFF_STATS;
    float* gpool  = ws + OFF_GPOOL;
    float* postbase = ws + OFF_P;   // post0..post3 = postbase + z*750000 (P/Q dead after k_agg)
    int* iw     = (int*)(ws + OFF_INT);
    int* cnt    = iw;
    int* eoff   = cnt + NN;        // NN+1
    int* cursor = eoff + NN + 2;
    int* esrc   = cursor + NN;
    int* ecombo = esrc + NE;

    k_zero_cnt<<<40, 256, 0, stream>>>(cnt);
    k_h0<<<640, 256, 0, stream>>>(x, node_emb, pre_lin_W, pre_lin_b, h);
    k_hist<<<625, 256, 0, stream>>>(edge_index, cnt);
    k_scan<<<1, 256, 0, stream>>>(cnt, eoff);
    k_nodestats<<<40, 256, 0, stream>>>(cnt, eoff, invdeg, amp, att, cursor);
    k_scatter<<<625, 256, 0, stream>>>(edge_index, edge_attr, cursor, esrc, ecombo);

    for (int l = 0; l < NL; l++){
        k_pq<<<319, 384, 0, stream>>>(h, preW, preb, edge_emb, encW, encb, l,
                                      P, Q, Rlut, stats);
        k_agg<<<dim3(NN, 2), 192, 0, stream>>>(P, Q, Rlut, eoff, esrc, ecombo, invdeg, agg);
        k_post<<<dim3(40, 5, 4), 256, 0, stream>>>(h, agg, postW, postb, amp, att, l, postbase);
        k_lin<<<313, 256, 0, stream>>>(postbase, linW, linb, l, hc, stats);
        k_bnapply<<<2930, 256, 0, stream>>>(hc, stats, bng, bnb, l, h);
    }

    k_pool<<<NG, 256, 0, stream>>>(h, batch, gpool);
    k_mlp<<<8, 256, 0, stream>>>(gpool, mlpW1, mlpb1, mlpW2, mlpb2, mlpW3, mlpb3, (float*)d_out);
}

// Round 8
// 970.149 us; speedup vs baseline: 1.8020x; 1.0775x over previous
//
#include <hip/hip_runtime.h>
#include <math.h>

#define NN 10000
#define NE 160000
#define NG 64
#define NT 5
#define NL 4
#define ADL 2.833213344056216f

// ws layout (float offsets)
#define OFF_H      0
#define OFF_HC     750000
#define OFF_P      1500000     // P during agg; reused as post partials z=0..6 after k_agg
#define OFF_Q      5250000
#define OFF_AGG    9000000
#define OFF_RLUT   24000000
#define OFF_INVDEG 24006000
#define OFF_AMP    24016000
#define OFF_ATT    24026000
#define OFF_STATS  24036000
#define OFF_GPOOL  24036160
#define OFF_INT    24118960

__global__ void k_zero_cnt(int* cnt){
    int i = blockIdx.x*256 + threadIdx.x;
    if (i < NN) cnt[i] = 0;
}

// h0 = node_emb[x].reshape(N,150) @ pre_lin_W + b
__global__ __launch_bounds__(256) void k_h0(const int* __restrict__ x,
        const float* __restrict__ node_emb, const float* __restrict__ plW,
        const float* __restrict__ plb, float* __restrict__ h){
    __shared__ float s_emb[21*75];
    __shared__ float s_W[150*75];
    __shared__ float s_b[75];
    int tid = threadIdx.x;
    for (int i = tid; i < 21*75; i += 256) s_emb[i] = node_emb[i];
    for (int i = tid; i < 150*75; i += 256) s_W[i] = plW[i];
    if (tid < 75) s_b[tid] = plb[tid];
    __syncthreads();
    for (int out = blockIdx.x*256 + tid; out < NN*75; out += gridDim.x*256){
        int n = out / 75, f = out - n*75;
        int x0 = x[2*n], x1 = x[2*n+1];
        float acc = s_b[f];
        const float* e0 = s_emb + x0*75;
        const float* e1 = s_emb + x1*75;
        #pragma unroll 5
        for (int k = 0; k < 75; k++)
            acc += e0[k]*s_W[k*75+f] + e1[k]*s_W[(75+k)*75+f];
        h[out] = acc;
    }
}

__global__ void k_hist(const int* __restrict__ ei, int* __restrict__ cnt){
    int e = blockIdx.x*256 + threadIdx.x;
    if (e < NE) atomicAdd(&cnt[ei[NE + e]], 1);
}

// single-block prefix sum: eoff[0]=0, eoff[n+1]=inclusive prefix
__global__ void k_scan(const int* __restrict__ cnt, int* __restrict__ eoff){
    __shared__ int buf[256];
    __shared__ int carry;
    int tid = threadIdx.x;
    if (tid == 0){ carry = 0; eoff[0] = 0; }
    __syncthreads();
    for (int base = 0; base < NN; base += 256){
        int v = (base + tid < NN) ? cnt[base + tid] : 0;
        buf[tid] = v; __syncthreads();
        for (int off = 1; off < 256; off <<= 1){
            int t2 = (tid >= off) ? buf[tid - off] : 0;
            __syncthreads();
            buf[tid] += t2;
            __syncthreads();
        }
        int inc = buf[tid] + carry;
        if (base + tid < NN) eoff[base + tid + 1] = inc;
        __syncthreads();
        if (tid == 255) carry = inc;
        __syncthreads();
    }
}

__global__ void k_nodestats(const int* __restrict__ cnt, const int* __restrict__ eoff,
        float* __restrict__ invdeg, float* __restrict__ amp, float* __restrict__ att,
        int* __restrict__ cursor){
    int n = blockIdx.x*256 + threadIdx.x;
    if (n >= NN) return;
    int c = cnt[n];
    cursor[n] = eoff[n];
    float cf = (float)c;
    float dg = cf < 1.f ? 1.f : cf;
    invdeg[n] = 1.f / dg;
    float ld = logf(dg + 1.f);
    amp[n] = ld / ADL;
    att[n] = ADL / ld;
}

__global__ void k_scatter(const int* __restrict__ ei, const int* __restrict__ ea,
        int* __restrict__ cursor, int* __restrict__ esrc, int* __restrict__ ecombo){
    int e = blockIdx.x*256 + threadIdx.x;
    if (e >= NE) return;
    int src = ei[e], dst = ei[NE + e];
    int pos = atomicAdd(&cursor[dst], 1);
    esrc[pos] = src;
    ecombo[pos] = ea[2*e]*4 + ea[2*e+1];
}

// Fused kernel, grid 319 x 384:
//  bx <  313 : P = h @ Wa, Q = h @ Wb  (32 nodes/block)
//  bx 313-317: Rlut for tower t = bx-313 (LDS-staged encW/ev/Wc, coalesced)
//  bx == 318 : zero BN stats
__global__ __launch_bounds__(384) void k_pq(const float* __restrict__ h,
        const float* __restrict__ preW, const float* __restrict__ preb,
        const float* __restrict__ edge_emb, const float* __restrict__ encW,
        const float* __restrict__ encb, int l,
        float* __restrict__ P, float* __restrict__ Q,
        float* __restrict__ Rlut, float* __restrict__ stats){
    __shared__ float smem[10675];
    int tid = threadIdx.x;
    int bx = blockIdx.x;

    if (bx == 318){
        for (int i = tid; i < 150; i += 384) stats[i] = 0.f;
        return;
    }
    if (bx >= 313){
        // ---- Rlut for tower t ----
        int t = bx - 313;
        float* s_encW = smem;            // 50*75 = 3750
        float* s_ev   = smem + 3750;     // 16*75 = 1200
        float* s_wc   = smem + 4950;     // 75*75 = 5625
        float* s_ee   = smem + 10575;    // 100
        for (int i = tid; i < 3750; i += 384) s_encW[i] = encW[(size_t)l*3750 + i];
        for (int i = tid; i < 100; i += 384) s_ee[i] = edge_emb[i];
        const float* wcsrc = preW + (((size_t)(l*NT + t))*225 + 150)*75;
        for (int i = tid; i < 5625; i += 384) s_wc[i] = wcsrc[i];
        __syncthreads();
        for (int task = tid; task < 1200; task += 384){
            int b = task/75, m = task - 75*b;
            int a0 = b >> 2, a1 = b & 3;
            float s = encb[l*75 + m];
            for (int k = 0; k < 25; k++)
                s += s_ee[a0*25+k]*s_encW[k*75+m] + s_ee[a1*25+k]*s_encW[(25+k)*75+m];
            s_ev[task] = s;
        }
        __syncthreads();
        for (int task = tid; task < 1200; task += 384){
            int b = task/75, f = task - 75*b;
            float r = preb[((size_t)l*NT + t)*75 + f];
            const float* ev = s_ev + b*75;
            #pragma unroll 5
            for (int m = 0; m < 75; m++) r += ev[m]*s_wc[m*75 + f];
            Rlut[b*375 + t*75 + f] = r;
        }
        return;
    }

    // ---- P/Q ----
    float* h_t = smem;   // 32*76 = 2432
    int base = bx*32;
    for (int idx = tid; idx < 32*75; idx += 384){
        int i = idx/75, m = idx - 75*i;
        int n = base + i;
        h_t[i*76 + m] = (n < NN) ? h[(size_t)n*75 + m] : 0.f;
    }
    __syncthreads();
    int j = tid;
    if (j >= 375) return;
    int t = j/75, f = j - 75*t;
    const float* wbase = preW + ((size_t)(l*NT + t))*225*75 + f;
    float accP[32], accQ[32];
    #pragma unroll
    for (int i = 0; i < 32; i++){ accP[i] = 0.f; accQ[i] = 0.f; }
    for (int m = 0; m < 72; m += 4){
        float wa0 = wbase[(m+0)*75], wa1 = wbase[(m+1)*75];
        float wa2 = wbase[(m+2)*75], wa3 = wbase[(m+3)*75];
        float wb0 = wbase[(75+m+0)*75], wb1 = wbase[(75+m+1)*75];
        float wb2 = wbase[(75+m+2)*75], wb3 = wbase[(75+m+3)*75];
        #pragma unroll
        for (int i = 0; i < 32; i++){
            const float4 hv = *(const float4*)&h_t[i*76 + m];
            accP[i] += hv.x*wa0 + hv.y*wa1 + hv.z*wa2 + hv.w*wa3;
            accQ[i] += hv.x*wb0 + hv.y*wb1 + hv.z*wb2 + hv.w*wb3;
        }
    }
    for (int m = 72; m < 75; m++){
        float wa = wbase[m*75], wb = wbase[(75+m)*75];
        #pragma unroll
        for (int i = 0; i < 32; i++){
            float v = h_t[i*76 + m];
            accP[i] += v*wa; accQ[i] += v*wb;
        }
    }
    for (int i = 0; i < 32; i++){
        int n = base + i;
        if (n < NN){ P[(size_t)n*375 + j] = accP[i]; Q[(size_t)n*375 + j] = accQ[i]; }
    }
}

// grid (NN, 3), block 128: y covers j in [y*128, y*128+128) ∩ [0,375).
// Edge loop unrolled x4 with batched metadata loads -> 8 outstanding VMEM/wave.
__global__ __launch_bounds__(128) void k_agg(const float* __restrict__ P,
        const float* __restrict__ Q, const float* __restrict__ Rlut,
        const int* __restrict__ eoff, const int* __restrict__ esrc,
        const int* __restrict__ ecombo, const float* __restrict__ invdeg,
        float* __restrict__ agg){
    int n = blockIdx.x;
    int j = blockIdx.y*128 + threadIdx.x;
    if (j >= 375) return;
    int lo = eoff[n], hi = eoff[n+1];
    float p = P[(size_t)n*375 + j];
    float sum = 0.f, sq = 0.f, mn = 3.4e38f, mx = -3.4e38f;
    int e = lo;
    for (; e + 4 <= hi; e += 4){
        int s0 = esrc[e],   s1 = esrc[e+1],   s2 = esrc[e+2],   s3 = esrc[e+3];
        int c0 = ecombo[e], c1 = ecombo[e+1], c2 = ecombo[e+2], c3 = ecombo[e+3];
        float q0 = Q[(size_t)s0*375 + j];
        float q1 = Q[(size_t)s1*375 + j];
        float q2 = Q[(size_t)s2*375 + j];
        float q3 = Q[(size_t)s3*375 + j];
        float r0 = Rlut[c0*375 + j];
        float r1 = Rlut[c1*375 + j];
        float r2 = Rlut[c2*375 + j];
        float r3 = Rlut[c3*375 + j];
        float m0 = p + q0 + r0, m1 = p + q1 + r1;
        float m2 = p + q2 + r2, m3 = p + q3 + r3;
        sum += m0 + m1 + m2 + m3;
        sq  += m0*m0 + m1*m1 + m2*m2 + m3*m3;
        mn = fminf(mn, fminf(fminf(m0, m1), fminf(m2, m3)));
        mx = fmaxf(mx, fmaxf(fmaxf(m0, m1), fmaxf(m2, m3)));
    }
    for (; e < hi; e++){
        int s = esrc[e], cm = ecombo[e];
        float m = p + Q[(size_t)s*375 + j] + Rlut[cm*375 + j];
        sum += m; sq += m*m;
        mn = fminf(mn, m); mx = fmaxf(mx, m);
    }
    float id = invdeg[n];
    bool has = hi > lo;
    float mean = sum*id;
    float msq  = sq*id;
    float var = msq - mean*mean; var = var > 0.f ? var : 0.f;
    float sd = sqrtf(var + 1e-5f);
    float mnv = has ? mn : 0.f;
    float mxv = has ? mx : 0.f;
    int t = j/75, f = j - 75*t;
    float* a = agg + ((size_t)n*NT + t)*300;
    a[f] = mean; a[75+f] = mnv; a[150+f] = mxv; a[225+f] = sd;
}

// post einsum, LDS-tiled + 7-way k-split over blockIdx.z.
// z0: h-part (3 tiles, +bias, a1 only); z1..z6: 2 agg tiles (50 k) each.
// grid (40, 5, 7). Partials summed in k_lin.
#define TK 25
#define PADA 27
__global__ __launch_bounds__(256, 4) void k_post(const float* __restrict__ h,
        const float* __restrict__ agg, const float* __restrict__ postW,
        const float* __restrict__ postb, const float* __restrict__ amp,
        const float* __restrict__ att, int l, float* __restrict__ postbase){
    __shared__ float s_a[256*PADA];      // 27.6 KB activation tile
    __shared__ float s_w[3][TK*16];      // 4.8 KB weight tiles (f padded to 16)
    int t = blockIdx.y;
    int z = blockIdx.z;
    int nbase = blockIdx.x*256;
    int tid = threadIdx.x;
    int fg  = (tid & 3)*4;
    int sub = tid >> 2;
    const float* Wt = postW + ((size_t)(l*NT + t))*975*15;
    float a1[4][4], a2[4][4], a3[4][4];
    #pragma unroll
    for (int j = 0; j < 4; j++)
        #pragma unroll
        for (int f = 0; f < 4; f++){ a1[j][f]=0.f; a2[j][f]=0.f; a3[j][f]=0.f; }

    if (z == 0){
        // ---- h-part: k = 0..74, weight rows 0..74, a1 only ----
        for (int kt = 0; kt < 75; kt += TK){
            for (int idx = tid; idx < 256*TK; idx += 256){
                int row = idx / TK, c = idx - row*TK;
                int n = nbase + row;
                s_a[row*PADA + c] = (n < NN) ? h[(size_t)n*75 + kt + c] : 0.f;
            }
            for (int idx = tid; idx < TK*16; idx += 256){
                int c = idx >> 4, f = idx & 15;
                s_w[0][idx] = (f < 15) ? Wt[(kt + c)*15 + f] : 0.f;
            }
            __syncthreads();
            for (int k = 0; k < TK; k++){
                const float4 w1 = *(const float4*)&s_w[0][k*16 + fg];
                #pragma unroll
                for (int j = 0; j < 4; j++){
                    float v = s_a[(sub + 64*j)*PADA + k];
                    a1[j][0] += v*w1.x; a1[j][1] += v*w1.y;
                    a1[j][2] += v*w1.z; a1[j][3] += v*w1.w;
                }
            }
            __syncthreads();
        }
        const float* pb = postb + (l*NT + t)*15;
        #pragma unroll
        for (int j = 0; j < 4; j++){
            int n = nbase + sub + 64*j;
            if (n >= NN) continue;
            float* dst = postbase + (size_t)n*75 + t*15;
            #pragma unroll
            for (int f = 0; f < 4; f++)
                if (fg + f < 15) dst[fg + f] = a1[j][f] + pb[fg + f];
        }
        return;
    }

    // ---- agg part: 2 tiles, k in [(z-1)*50, (z-1)*50+50) ----
    int kbeg = (z-1)*50, kend = kbeg + 50;
    for (int kt = kbeg; kt < kend; kt += TK){
        for (int idx = tid; idx < 256*TK; idx += 256){
            int row = idx / TK, c = idx - row*TK;
            int n = nbase + row;
            s_a[row*PADA + c] = (n < NN) ? agg[(size_t)n*1500 + t*300 + kt + c] : 0.f;
        }
        for (int idx = tid; idx < TK*16; idx += 256){
            int c = idx >> 4, f = idx & 15;
            float v1 = 0.f, v2 = 0.f, v3 = 0.f;
            if (f < 15){
                v1 = Wt[( 75 + kt + c)*15 + f];
                v2 = Wt[(375 + kt + c)*15 + f];
                v3 = Wt[(675 + kt + c)*15 + f];
            }
            s_w[0][idx] = v1; s_w[1][idx] = v2; s_w[2][idx] = v3;
        }
        __syncthreads();
        for (int k = 0; k < TK; k++){
            const float4 w1 = *(const float4*)&s_w[0][k*16 + fg];
            const float4 w2 = *(const float4*)&s_w[1][k*16 + fg];
            const float4 w3 = *(const float4*)&s_w[2][k*16 + fg];
            #pragma unroll
            for (int j = 0; j < 4; j++){
                float v = s_a[(sub + 64*j)*PADA + k];
                a1[j][0] += v*w1.x; a1[j][1] += v*w1.y;
                a1[j][2] += v*w1.z; a1[j][3] += v*w1.w;
                a2[j][0] += v*w2.x; a2[j][1] += v*w2.y;
                a2[j][2] += v*w2.z; a2[j][3] += v*w2.w;
                a3[j][0] += v*w3.x; a3[j][1] += v*w3.y;
                a3[j][2] += v*w3.z; a3[j][3] += v*w3.w;
            }
        }
        __syncthreads();
    }

    float* postv = postbase + (size_t)z*750000;
    #pragma unroll
    for (int j = 0; j < 4; j++){
        int n = nbase + sub + 64*j;
        if (n >= NN) continue;
        float am = amp[n], at = att[n];
        float* dst = postv + (size_t)n*75 + t*15;
        #pragma unroll
        for (int f = 0; f < 4; f++)
            if (fg + f < 15)
                dst[fg + f] = a1[j][f] + am*a2[j][f] + at*a3[j][f];
    }
}

// hc = (Σz postz) @ lin_W[l] + lin_b[l]; fused per-block BN-stat reduction
__global__ __launch_bounds__(256) void k_lin(const float* __restrict__ postbase,
        const float* __restrict__ linW, const float* __restrict__ linb,
        int l, float* __restrict__ hc, float* __restrict__ stats){
    __shared__ float p_l[32*75];
    __shared__ float w_l[75*75];
    __shared__ float hc_l[32*75];
    int tid = threadIdx.x;
    int base = blockIdx.x*32;
    for (int i = tid; i < 75*75; i += 256) w_l[i] = linW[(size_t)l*5625 + i];
    for (int i = tid; i < 32*75; i += 256){
        int n = base + i/75;
        size_t idx = (size_t)base*75 + i;
        float v = 0.f;
        if (n < NN){
            #pragma unroll
            for (int z = 0; z < 7; z++) v += postbase[idx + (size_t)z*750000];
        }
        p_l[i] = v;
    }
    __syncthreads();
    for (int task = tid; task < 2400; task += 256){
        int i = task/75, o = task - 75*i;
        float s = linb[l*75 + o];
        const float* pl = p_l + i*75;
        #pragma unroll 5
        for (int j = 0; j < 75; j++) s += pl[j]*w_l[j*75 + o];
        hc_l[task] = s;
        if (base + i < NN) hc[(size_t)(base+i)*75 + o] = s;
    }
    __syncthreads();
    if (tid < 75){
        int nv = NN - base; if (nv > 32) nv = 32;
        float s1 = 0.f, s2 = 0.f;
        for (int i = 0; i < nv; i++){
            float v = hc_l[i*75 + tid];
            s1 += v; s2 += v*v;
        }
        atomicAdd(&stats[tid], s1);
        atomicAdd(&stats[75+tid], s2);
    }
}

__global__ void k_bnapply(const float* __restrict__ hc, const float* __restrict__ stats,
        const float* __restrict__ bng, const float* __restrict__ bnb, int l,
        float* __restrict__ h){
    int idx = blockIdx.x*256 + threadIdx.x;
    if (idx >= NN*75) return;
    int col = idx % 75;
    float mu = stats[col]*(1.0f/NN);
    float var = stats[75+col]*(1.0f/NN) - mu*mu;
    float inv = rsqrtf(var + 1e-5f);
    float v = (hc[idx] - mu)*inv*bng[l*75+col] + bnb[l*75+col];
    h[idx] = v > 0.f ? v : 0.f;
}

__global__ __launch_bounds__(256) void k_pool(const float* __restrict__ h,
        const int* __restrict__ batch, float* __restrict__ gpool){
    int g = blockIdx.x, tid = threadIdx.x;
    int lo = 0, hi = NN;
    while (lo < hi){ int mid = (lo+hi)>>1; if (batch[mid] < g) lo = mid+1; else hi = mid; }
    int start = lo;
    lo = start; hi = NN;
    while (lo < hi){ int mid = (lo+hi)>>1; if (batch[mid] < g+1) lo = mid+1; else hi = mid; }
    int end = lo;
    __shared__ float red[225];
    if (tid < 225){
        int col = tid % 75, rep = tid / 75;
        float acc = 0.f;
        for (int i = start + rep; i < end; i += 3) acc += h[(size_t)i*75 + col];
        red[tid] = acc;
    }
    __syncthreads();
    if (tid < 75) gpool[g*75 + tid] = red[tid] + red[75+tid] + red[150+tid];
}

// 8 blocks x 8 graphs; weights in LDS, phase-parallel
__global__ __launch_bounds__(256) void k_mlp(const float* __restrict__ gpool,
        const float* __restrict__ W1, const float* __restrict__ b1,
        const float* __restrict__ W2, const float* __restrict__ b2,
        const float* __restrict__ W3, const float* __restrict__ b3,
        float* __restrict__ out){
    __shared__ float w1[75*50];
    __shared__ float w2[50*25];
    __shared__ float gp[8*75];
    __shared__ float t1[8*50];
    __shared__ float t2[8*25];
    int tid = threadIdx.x;
    int gbase = blockIdx.x*8;
    for (int i = tid; i < 75*50; i += 256) w1[i] = W1[i];
    for (int i = tid; i < 50*25; i += 256) w2[i] = W2[i];
    for (int i = tid; i < 8*75; i += 256) gp[i] = gpool[gbase*75 + i];
    __syncthreads();
    for (int task = tid; task < 8*50; task += 256){
        int g = task/50, j = task - 50*g;
        float s = b1[j];
        const float* gv = gp + g*75;
        #pragma unroll 5
        for (int k = 0; k < 75; k++) s += gv[k]*w1[k*50+j];
        t1[task] = s > 0.f ? s : 0.f;
    }
    __syncthreads();
    for (int task = tid; task < 8*25; task += 256){
        int g = task/25, j = task - 25*g;
        float s = b2[j];
        const float* tv = t1 + g*50;
        #pragma unroll 5
        for (int k = 0; k < 50; k++) s += tv[k]*w2[k*25+j];
        t2[task] = s > 0.f ? s : 0.f;
    }
    __syncthreads();
    if (tid < 8){
        float s = b3[0];
        const float* tv = t2 + tid*25;
        #pragma unroll
        for (int k = 0; k < 25; k++) s += tv[k]*W3[k];
        out[gbase + tid] = s;
    }
}

extern "C" void kernel_launch(void* const* d_in, const int* in_sizes, int n_in,
                              void* d_out, int out_size, void* d_ws, size_t ws_size,
                              hipStream_t stream){
    const int* x          = (const int*)d_in[0];
    const int* edge_index = (const int*)d_in[1];
    const int* edge_attr  = (const int*)d_in[2];
    const int* batch      = (const int*)d_in[3];
    const float* node_emb = (const float*)d_in[4];
    const float* edge_emb = (const float*)d_in[5];
    const float* pre_lin_W= (const float*)d_in[6];
    const float* pre_lin_b= (const float*)d_in[7];
    const float* encW     = (const float*)d_in[8];
    const float* encb     = (const float*)d_in[9];
    const float* preW     = (const float*)d_in[10];
    const float* preb     = (const float*)d_in[11];
    const float* postW    = (const float*)d_in[12];
    const float* postb    = (const float*)d_in[13];
    const float* linW     = (const float*)d_in[14];
    const float* linb     = (const float*)d_in[15];
    const float* bng      = (const float*)d_in[16];
    const float* bnb      = (const float*)d_in[17];
    const float* mlpW1    = (const float*)d_in[18];
    const float* mlpb1    = (const float*)d_in[19];
    const float* mlpW2    = (const float*)d_in[20];
    const float* mlpb2    = (const float*)d_in[21];
    const float* mlpW3    = (const float*)d_in[22];
    const float* mlpb3    = (const float*)d_in[23];

    float* ws = (float*)d_ws;
    float* h      = ws + OFF_H;
    float* hc     = ws + OFF_HC;
    float* P      = ws + OFF_P;
    float* Q      = ws + OFF_Q;
    float* agg    = ws + OFF_AGG;
    float* Rlut   = ws + OFF_RLUT;
    float* invdeg = ws + OFF_INVDEG;
    float* amp    = ws + OFF_AMP;
    float* att    = ws + OFF_ATT;
    float* stats  = ws + OFF_STATS;
    float* gpool  = ws + OFF_GPOOL;
    float* postbase = ws + OFF_P;   // post partials z=0..6 at postbase + z*750000
    int* iw     = (int*)(ws + OFF_INT);
    int* cnt    = iw;
    int* eoff   = cnt + NN;        // NN+1
    int* cursor = eoff + NN + 2;
    int* esrc   = cursor + NN;
    int* ecombo = esrc + NE;

    k_zero_cnt<<<40, 256, 0, stream>>>(cnt);
    k_h0<<<640, 256, 0, stream>>>(x, node_emb, pre_lin_W, pre_lin_b, h);
    k_hist<<<625, 256, 0, stream>>>(edge_index, cnt);
    k_scan<<<1, 256, 0, stream>>>(cnt, eoff);
    k_nodestats<<<40, 256, 0, stream>>>(cnt, eoff, invdeg, amp, att, cursor);
    k_scatter<<<625, 256, 0, stream>>>(edge_index, edge_attr, cursor, esrc, ecombo);

    for (int l = 0; l < NL; l++){
        k_pq<<<319, 384, 0, stream>>>(h, preW, preb, edge_emb, encW, encb, l,
                                      P, Q, Rlut, stats);
        k_agg<<<dim3(NN, 3), 128, 0, stream>>>(P, Q, Rlut, eoff, esrc, ecombo, invdeg, agg);
        k_post<<<dim3(40, 5, 7), 256, 0, stream>>>(h, agg, postW, postb, amp, att, l, postbase);
        k_lin<<<313, 256, 0, stream>>>(postbase, linW, linb, l, hc, stats);
        k_bnapply<<<2930, 256, 0, stream>>>(hc, stats, bng, bnb, l, h);
    }

    k_pool<<<NG, 256, 0, stream>>>(h, batch, gpool);
    k_mlp<<<8, 256, 0, stream>>>(gpool, mlpW1, mlpb1, mlpW2, mlpb2, mlpW3, mlpb3, (float*)d_out);
}